// Round 6
// baseline (770.527 us; speedup 1.0000x reference)
//
#include <hip/hip_runtime.h>
#include <math.h>

// Problem constants
#define NB   512   // B (agents)
#define NBLK 256   // fused-path blocks (2 agents per block)
#define NH   64    // H = E = HP
#define OBS  8
#define PRE  12

// small f32 param pack offsets (elements)
#define OFF_WREL  0     // 128
#define OFF_BREL  128   // 64
#define OFF_BPOOL 192   // 64
#define OFF_WPOS  256   // 128
#define OFF_BPOS  384   // 2
#define OFF_WEMB  386   // 128
#define OFF_BEMB  514   // 64
#define OFF_BIH   578   // 192
#define OFF_BHH   770   // 192
#define OFF_FLAG  962   // 1: 1.0 if buffers are f32, 0.0 if bf16
#define N_SMALL   963

// ---- fused-path workspace layout (page-gapped write-once buffers) ----------
#define WS_BAR    0         // 4096 B (barrier counters, zeroed by init_kernel)
#define WS_SMALL  4096      // 4096 B (963 f32 used)
#define WS_WTF    8192      // 98304 B
#define WS_WPBF   106496    // 16384 B
#define WS_LAST   122880    // 13 * 8192 B   (4 KB data + 4 KB page gap each)
#define WS_HBF    229376    // 13 * 69632 B  (64 KB data + 4 KB page gap each)
#define WS_TOTAL  1134592
#define LAST_STRIDE_F2  1024   // float2 elems per last buffer slot
#define HBF_STRIDE_U16  34816  // u16 elems per hbf buffer slot

typedef __bf16 bf16x8 __attribute__((ext_vector_type(8)));
typedef float  f32x4  __attribute__((ext_vector_type(4)));

union FragU { bf16x8 v; unsigned short u[8]; };

__device__ __forceinline__ float bf2f(unsigned short u) {
  unsigned int x = ((unsigned int)u) << 16;
  return __builtin_bit_cast(float, x);
}
__device__ __forceinline__ unsigned short f2bf(float f) {
  unsigned int u = __builtin_bit_cast(unsigned int, f);
  u += 0x7FFFu + ((u >> 16) & 1u);   // RNE
  return (unsigned short)(u >> 16);
}
__device__ __forceinline__ float ldf(const void* p, int i, bool isf32) {
  return isf32 ? ((const float*)p)[i] : bf2f(((const unsigned short*)p)[i]);
}
__device__ __forceinline__ unsigned short ld16(const void* p, int i, bool isf32) {
  return isf32 ? f2bf(((const float*)p)[i]) : ((const unsigned short*)p)[i];
}
__device__ __forceinline__ void stout(void* p, int i, float v, bool isf32) {
  if (isf32) ((float*)p)[i] = v;
  else       ((unsigned short*)p)[i] = f2bf(v);
}

// ---- device-coherent stores: write-through to the IC coherence point so
// consumers on other XCDs see fresh data on their (plain, cached) first touch.
__device__ __forceinline__ void st32_sc(unsigned* p, unsigned v) {
  __hip_atomic_store(p, v, __ATOMIC_RELAXED, __HIP_MEMORY_SCOPE_AGENT);
}
__device__ __forceinline__ void stf_sc(float* p, float v) {
  __hip_atomic_store(p, v, __ATOMIC_RELAXED, __HIP_MEMORY_SCOPE_AGENT);
}
__device__ __forceinline__ void st64_sc(void* p, unsigned long long v) {
  __hip_atomic_store((unsigned long long*)p, v, __ATOMIC_RELAXED, __HIP_MEMORY_SCOPE_AGENT);
}

// ---- 2-level tree barrier in workspace for NBLK=256 blocks.
// bar[0..15]=leaf (16 blocks each), bar[64]=root, bar[96]=release (rounds).
// Counters monotonic; init_kernel zeroes. __syncthreads() at entry drains all
// waves' vm ops (compiler emits full waitcnt before s_barrier), so prior
// sc-stores are IC-visible before the arrival is published.
__device__ __forceinline__ void grid_barrier(unsigned* bar, unsigned phase,
                                             int tid, int bid) {
  __syncthreads();
  if (tid == 0) {
    asm volatile("s_waitcnt vmcnt(0)" ::: "memory");
    unsigned prev = __hip_atomic_fetch_add(&bar[bid & 15], 1u,
                                           __ATOMIC_RELAXED, __HIP_MEMORY_SCOPE_AGENT);
    if ((prev & 15u) == 15u) {
      unsigned r = __hip_atomic_fetch_add(&bar[64], 1u,
                                          __ATOMIC_RELAXED, __HIP_MEMORY_SCOPE_AGENT);
      if ((r & 15u) == 15u) {
        __hip_atomic_store(&bar[96], (r >> 4) + 1u,
                           __ATOMIC_RELAXED, __HIP_MEMORY_SCOPE_AGENT);
      }
    }
    while (__hip_atomic_load(&bar[96], __ATOMIC_RELAXED,
                             __HIP_MEMORY_SCOPE_AGENT) < phase)
      __builtin_amdgcn_s_sleep(2);
  }
  __syncthreads();
}

__global__ __launch_bounds__(128) void init_kernel(unsigned* bar) {
  bar[threadIdx.x] = 0;
}

// ---------------------------------------------------------------------------
// FUSED persistent kernel: prep + all 12 decoder steps. 256 blocks x 1024
// threads (16 waves), TWO agents per block (waves 0-7 -> agent 2*bid,
// waves 8-15 -> agent 2*bid+1).
// Deadlock-safety: 256 blocks on 256 CUs with per-CU capacity >= 1 block
// (16 waves <= 32/CU, ~33 KB LDS, VGPR forced <= 128 by the 1024-thread
// launch bound) means ALL blocks are resident under any scheduler placement
// -- no launch_bounds second-arg gamble (round-5 failure mode).
// Occupancy: 16 waves/CU = 4/SIMD, 2x round 4's latency hiding.
// Cross-step state via per-step write-once buffers: producers sc-store
// (write-through to IC), consumers plain cached loads after the barrier.
// ---------------------------------------------------------------------------
__global__ __launch_bounds__(1024) void fused_kernel(
    const void* __restrict__ hidden_state, // (1,512,64)
    const void* __restrict__ group_track,  // (512,8,2)
    const void* __restrict__ W_emb,  const void* __restrict__ b_emb,
    const void* __restrict__ W_ih,   const void* __restrict__ W_hh,
    const void* __restrict__ b_ih,   const void* __restrict__ b_hh,
    const void* __restrict__ W_pos,  const void* __restrict__ b_pos,
    const void* __restrict__ W_rel,  const void* __restrict__ b_rel,
    const void* __restrict__ W_pool, const void* __restrict__ b_pool,
    float2* __restrict__ lastbase,         // 13 slots, stride LAST_STRIDE_F2
    unsigned short* __restrict__ hbfbase,  // 13 slots, stride HBF_STRIDE_U16
    float* __restrict__ WTf,               // (64,384) f32 transposed GRU W
    unsigned short* __restrict__ Wp_bf,    // (128,64) bf16 W_pool
    float* __restrict__ smallf,            // N_SMALL f32 param pack
    unsigned* __restrict__ bar,            // barrier counters (zeroed)
    void* __restrict__ out)                // (512,20,2) dtype = input dtype
{
  const int bid  = blockIdx.x;
  const int tid  = threadIdx.x;   // 0..1023
  const int lane = tid & 63;
  const int wave = tid >> 6;      // 0..15
  const int ag   = wave >> 3;     // 0..1  (agent slot within block)
  const int wv   = wave & 7;      // 0..7  (wave within agent)
  const int i    = 2 * bid + ag;  // global agent id
  const int col  = lane & 15;     // MFMA m (A rows) / n (B cols) index
  const int quad = lane >> 4;     // selects k-group (quad*8 .. quad*8+7)

  __shared__ float  red[2][8][64];
  __shared__ float  part[2][8][6][64];
  __shared__ float  hstate[2][64];       // per-agent f32 GRU carry
  __shared__ float2 lpos[512];           // per-step staged last positions

  // ======================= prep ==========================
  // dtype detect: bf16-interpret first 256 u16 of hidden_state. Identical
  // wave-uniform result in every wave.
  int bad = 0;
  const unsigned short* hs16 = (const unsigned short*)hidden_state;
  for (int k = lane; k < 256; k += 64) {
    unsigned e = (hs16[k] >> 7) & 0xFFu;
    bad |= (e >= 0x8Eu) ? 1 : 0;
  }
  const bool isf32 = (__ballot(bad) != 0ULL);

  if (tid < 64) {                      // both agents' h0 rows -> bf16 u32, sc
    int a2 = tid >> 5, w32 = tid & 31;
    int ii = 2 * bid + a2;
    unsigned lo = ld16(hidden_state, ii * 64 + 2 * w32,     isf32);
    unsigned hi = ld16(hidden_state, ii * 64 + 2 * w32 + 1, isf32);
    st32_sc((unsigned*)hbfbase + ii * 32 + w32, lo | (hi << 16));
  }
  if (tid < 128) hstate[tid >> 6][tid & 63] = 0.0f;
  if (tid < 32) {                      // observed track -> out, both agents
    int a2 = tid >> 4, k = tid & 15;
    int ii = 2 * bid + a2;
    stout(out, ii * 40 + k, ldf(group_track, ii * 16 + k, isf32), isf32);
  }
  if (tid < 2) {                       // last0, both agents
    int ii = 2 * bid + tid;
    float2 l0;
    l0.x = ldf(group_track, ii * 16 + 14, isf32);
    l0.y = ldf(group_track, ii * 16 + 15, isf32);
    st64_sc(lastbase + ii, __builtin_bit_cast(unsigned long long, l0));
  }

  if (bid < 24) {                      // WTf: 24576 elems = 24 blocks x 1024
    int u = bid * 1024 + tid;
    int k = u / 384, c = u % 384;
    float v = (c < 192) ? ldf(W_ih, c * 64 + k, isf32)
                        : ldf(W_hh, (c - 192) * 64 + k, isf32);
    stf_sc(&WTf[u], v);
  } else if (bid < 28) {               // Wp_bf: 4096 u32 = 4 blocks x 1024
    int u = (bid - 24) * 1024 + tid;
    unsigned lo = ld16(W_pool, 2 * u,     isf32);
    unsigned hi = ld16(W_pool, 2 * u + 1, isf32);
    st32_sc((unsigned*)Wp_bf + u, lo | (hi << 16));
  } else if (bid == 28) {              // smallf pack: 963 elems
    int u = tid;
    if (u < N_SMALL) {
      float v;
      if      (u < 128) v = ldf(W_rel,  u,        isf32);
      else if (u < 192) v = ldf(b_rel,  u - 128,  isf32);
      else if (u < 256) v = ldf(b_pool, u - 192,  isf32);
      else if (u < 384) v = ldf(W_pos,  u - 256,  isf32);
      else if (u < 386) v = ldf(b_pos,  u - 384,  isf32);
      else if (u < 514) v = ldf(W_emb,  u - 386,  isf32);
      else if (u < 578) v = ldf(b_emb,  u - 514,  isf32);
      else if (u < 770) v = ldf(b_ih,   u - 578,  isf32);
      else if (u < 962) v = ldf(b_hh,   u - 770,  isf32);
      else              v = isf32 ? 1.0f : 0.0f;   // OFF_FLAG
      stf_sc(&smallf[u], v);
    }
  }
  grid_barrier(bar, 1u, tid, bid);

  // =================== persistent per-lane fragments =======================
  // Write-once data: plain cached loads, first touch is after the barrier.
  float wr0[2][8], wr1[2][8], brl[2][8];
  #pragma unroll
  for (int ks = 0; ks < 2; ++ks) {
    int kb = ks * 32 + quad * 8;
    #pragma unroll
    for (int j = 0; j < 8; ++j) {
      wr0[ks][j] = smallf[OFF_WREL + kb + j];
      wr1[ks][j] = smallf[OFF_WREL + 64 + kb + j];
      brl[ks][j] = smallf[OFF_BREL + kb + j];
    }
  }
  float bp[4];
  #pragma unroll
  for (int nt = 0; nt < 4; ++nt) bp[nt] = smallf[OFF_BPOOL + nt * 16 + col];

  // B-operand fragments of full W_pool (K=128): lane holds
  // B[k = ks*32 + quad*8 + j][n = nt*16 + col]
  FragU bw[4][4];
  #pragma unroll
  for (int nt = 0; nt < 4; ++nt)
    #pragma unroll
    for (int ks = 0; ks < 4; ++ks)
      #pragma unroll
      for (int j = 0; j < 8; ++j)
        bw[nt][ks].u[j] = Wp_bf[(ks * 32 + quad * 8 + j) * 64 + nt * 16 + col];

  // ========================== decode loop ==================================
  for (int t = 0; t < PRE; ++t) {
    // step-t buffers are ready (barrier passed); all loads below are plain.
    const float2*         lp       = lastbase + t * LAST_STRIDE_F2;
    float2*               last_out = lastbase + (t + 1) * LAST_STRIDE_F2;
    const unsigned short* hbf_in   = hbfbase + t * HBF_STRIDE_U16;
    unsigned short*       hbf_out  = hbfbase + (t + 1) * HBF_STRIDE_U16;

    if (tid < 512) lpos[tid] = lp[tid];  // stage all 512 positions in LDS
    __syncthreads();
    const float2 li = lpos[i];

    float vmax[4] = {0.f, 0.f, 0.f, 0.f};  // m = relu(..) >= 0, so 0 is safe

    // --- j loop: this wave covers rows [wv*64, wv*64+64), 32 at a time
    const int jb0 = wv * 64;
    #pragma unroll
    for (int s = 0; s < 2; ++s) {
      const int jb = jb0 + s * 32;
      const int r0 = jb + col, r1 = r0 + 16;
      const float2 l0 = lpos[r0], l1 = lpos[r1];
      const float d0x = l0.x - li.x, d0y = l0.y - li.y;
      const float d1x = l1.x - li.x, d1y = l1.y - li.y;

      // A-fragments for e-part (K rows 0..63)
      FragU aE[2][2];
      #pragma unroll
      for (int ks = 0; ks < 2; ++ks) {
        #pragma unroll
        for (int j = 0; j < 8; ++j) {
          float e0 = fmaxf(d0x * wr0[ks][j] + d0y * wr1[ks][j] + brl[ks][j], 0.f);
          float e1 = fmaxf(d1x * wr0[ks][j] + d1y * wr1[ks][j] + brl[ks][j], 0.f);
          aE[0][ks].u[j] = f2bf(e0);
          aE[1][ks].u[j] = f2bf(e1);
        }
      }
      // A-fragments for h-part (K rows 64..127): plain 16B vector loads
      bf16x8 aH[2][2];
      #pragma unroll
      for (int mt = 0; mt < 2; ++mt) {
        int jr = jb + mt * 16 + col;
        #pragma unroll
        for (int ks = 0; ks < 2; ++ks)
          aH[mt][ks] = *(const bf16x8*)(hbf_in + jr * 64 + ks * 32 + quad * 8);
      }

      f32x4 acc[2][4];
      #pragma unroll
      for (int mt = 0; mt < 2; ++mt)
        #pragma unroll
        for (int nt = 0; nt < 4; ++nt)
          acc[mt][nt] = (f32x4){0.f, 0.f, 0.f, 0.f};

      #pragma unroll
      for (int nt = 0; nt < 4; ++nt)
        #pragma unroll
        for (int mt = 0; mt < 2; ++mt) {
          acc[mt][nt] = __builtin_amdgcn_mfma_f32_16x16x32_bf16(aE[mt][0].v, bw[nt][0].v, acc[mt][nt], 0, 0, 0);
          acc[mt][nt] = __builtin_amdgcn_mfma_f32_16x16x32_bf16(aE[mt][1].v, bw[nt][1].v, acc[mt][nt], 0, 0, 0);
          acc[mt][nt] = __builtin_amdgcn_mfma_f32_16x16x32_bf16(aH[mt][0],   bw[nt][2].v, acc[mt][nt], 0, 0, 0);
          acc[mt][nt] = __builtin_amdgcn_mfma_f32_16x16x32_bf16(aH[mt][1],   bw[nt][3].v, acc[mt][nt], 0, 0, 0);
        }

      // epilogue: + b_pool, relu, running max over rows (fuses to v_max3)
      #pragma unroll
      for (int mt = 0; mt < 2; ++mt)
        #pragma unroll
        for (int nt = 0; nt < 4; ++nt)
          #pragma unroll
          for (int r = 0; r < 4; ++r) {
            float v = acc[mt][nt][r] + bp[nt];
            vmax[nt] = fmaxf(fmaxf(v, 0.f), vmax[nt]);
          }
    }

    // reduce over quads within the wave, publish per-wave max
    #pragma unroll
    for (int nt = 0; nt < 4; ++nt) {
      vmax[nt] = fmaxf(vmax[nt], __shfl_xor(vmax[nt], 16, 64));
      vmax[nt] = fmaxf(vmax[nt], __shfl_xor(vmax[nt], 32, 64));
    }
    if (lane < 16) {
      #pragma unroll
      for (int nt = 0; nt < 4; ++nt) red[ag][wv][nt * 16 + lane] = vmax[nt];
    }
    __syncthreads();   // sync1: red[] complete; hstate stable from prev step

    // ---------- head: pos -> emb -> GRU, 8-way wave-parallel per agent -----
    {
      const int o = lane;
      float pooled = fmaxf(fmaxf(fmaxf(red[ag][0][o], red[ag][1][o]),
                                 fmaxf(red[ag][2][o], red[ag][3][o])),
                           fmaxf(fmaxf(red[ag][4][o], red[ag][5][o]),
                                 fmaxf(red[ag][6][o], red[ag][7][o])));
      float p0 = pooled * smallf[OFF_WPOS + o * 2 + 0];
      float p1 = pooled * smallf[OFF_WPOS + o * 2 + 1];
      #pragma unroll
      for (int sft = 32; sft >= 1; sft >>= 1) {
        p0 += __shfl_xor(p0, sft, 64);
        p1 += __shfl_xor(p1, sft, 64);
      }
      p0 += smallf[OFF_BPOS + 0];
      p1 += smallf[OFF_BPOS + 1];

      // wave wv accumulates k in [8wv, 8wv+8): partial 6 gate mat-vecs
      float g0 = 0.f, g1 = 0.f, g2 = 0.f, g3 = 0.f, g4 = 0.f, g5 = 0.f;
      #pragma unroll
      for (int kk = 0; kk < 8; ++kk) {
        int k = wv * 8 + kk;
        float ek = p0 * smallf[OFF_WEMB + k] + p1 * smallf[OFF_WEMB + 64 + k]
                 + smallf[OFF_BEMB + k];          // emb_k (uniform)
        float hk = hstate[ag][k];                 // uniform LDS broadcast
        const float* w = WTf + k * 384;           // coalesced across lanes
        g0 += ek * w[o];
        g1 += ek * w[64 + o];
        g2 += ek * w[128 + o];
        g3 += hk * w[192 + o];
        g4 += hk * w[256 + o];
        g5 += hk * w[320 + o];
      }
      part[ag][wv][0][o] = g0; part[ag][wv][1][o] = g1; part[ag][wv][2][o] = g2;
      part[ag][wv][3][o] = g3; part[ag][wv][4][o] = g4; part[ag][wv][5][o] = g5;
      __syncthreads();   // sync2: partials complete; hstate reads done

      if (wv == 0) {     // waves 0 and 8: one finisher wave per agent
        float gir = 0.f, giz = 0.f, gin = 0.f, ghr = 0.f, ghz = 0.f, ghn = 0.f;
        #pragma unroll
        for (int pp = 0; pp < 8; ++pp) {
          gir += part[ag][pp][0][o]; giz += part[ag][pp][1][o]; gin += part[ag][pp][2][o];
          ghr += part[ag][pp][3][o]; ghz += part[ag][pp][4][o]; ghn += part[ag][pp][5][o];
        }
        gir += smallf[OFF_BIH + o];       ghr += smallf[OFF_BHH + o];
        giz += smallf[OFF_BIH + 64 + o];  ghz += smallf[OFF_BHH + 64 + o];
        gin += smallf[OFF_BIH + 128 + o]; ghn += smallf[OFF_BHH + 128 + o];
        float r = 1.f / (1.f + __expf(-(gir + ghr)));
        float z = 1.f / (1.f + __expf(-(giz + ghz)));
        float n = tanhf(gin + r * ghn);
        float hp = hstate[ag][o];
        float hn = (1.f - z) * n + z * hp;
        hstate[ag][o] = hn;                  // safe: all reads were pre-sync2
        // pack bf16 pairs, sc-store as u32 into next step's write-once buf
        int hbi = (int)f2bf(hn);
        unsigned v0 = (unsigned)__shfl(hbi, (o & 31) * 2, 64);
        unsigned v1 = (unsigned)__shfl(hbi, (o & 31) * 2 + 1, 64);
        if (o < 32)
          st32_sc((unsigned*)hbf_out + i * 32 + o, v0 | (v1 << 16));
        if (o == 0) {
          stout(out, i * 40 + (OBS + t) * 2 + 0, p0, isf32);
          stout(out, i * 40 + (OBS + t) * 2 + 1, p1, isf32);
          float2 pr; pr.x = p0; pr.y = p1;
          st64_sc(last_out + i, __builtin_bit_cast(unsigned long long, pr));
        }
      }
    }

    if (t < PRE - 1) grid_barrier(bar, (unsigned)(t + 2), tid, bid);
  }
}

// ---------------------------------------------------------------------------
// FALLBACK path (known-good 13-launch version) if workspace is too small.
// Uses its own (old) compact workspace layout.
// ---------------------------------------------------------------------------
__global__ __launch_bounds__(64) void prep_kernel(
    const void* __restrict__ hidden_state,
    const void* __restrict__ group_track,
    const void* __restrict__ W_emb,  const void* __restrict__ b_emb,
    const void* __restrict__ W_ih,   const void* __restrict__ W_hh,
    const void* __restrict__ b_ih,   const void* __restrict__ b_hh,
    const void* __restrict__ W_pos,  const void* __restrict__ b_pos,
    const void* __restrict__ W_rel,  const void* __restrict__ b_rel,
    const void* __restrict__ W_pool, const void* __restrict__ b_pool,
    float* __restrict__ last0,
    unsigned short* __restrict__ hbf0,
    float* __restrict__ h_carry,
    float* __restrict__ WTf,
    unsigned short* __restrict__ Wp_bf,
    float* __restrict__ smallf,
    void* __restrict__ out)
{
  const int b = blockIdx.x;
  const int o = threadIdx.x;

  int bad = 0;
  const unsigned short* hs16 = (const unsigned short*)hidden_state;
  for (int k = o; k < 256; k += 64) {
    unsigned e = (hs16[k] >> 7) & 0xFFu;
    bad |= (e >= 0x8Eu) ? 1 : 0;
  }
  const bool isf32 = (__ballot(bad) != 0ULL);

  hbf0[b * 64 + o] = ld16(hidden_state, b * 64 + o, isf32);
  h_carry[b * 64 + o] = 0.0f;
  if (o < 16) stout(out, b * 40 + o, ldf(group_track, b * 16 + o, isf32), isf32);
  if (o < 2)  last0[b * 2 + o] = ldf(group_track, b * 16 + 14 + o, isf32);

  if (b < 384) {
    int u = b * 64 + o;
    int k = u / 384, c = u % 384;
    WTf[u] = (c < 192) ? ldf(W_ih, c * 64 + k, isf32)
                       : ldf(W_hh, (c - 192) * 64 + k, isf32);
  } else {
    int u = (b - 384) * 64 + o;
    Wp_bf[u] = ld16(W_pool, u, isf32);
  }

  if (b < 16) {
    int u = b * 64 + o;
    if (u < N_SMALL) {
      float v;
      if      (u < 128) v = ldf(W_rel,  u,        isf32);
      else if (u < 192) v = ldf(b_rel,  u - 128,  isf32);
      else if (u < 256) v = ldf(b_pool, u - 192,  isf32);
      else if (u < 384) v = ldf(W_pos,  u - 256,  isf32);
      else if (u < 386) v = ldf(b_pos,  u - 384,  isf32);
      else if (u < 514) v = ldf(W_emb,  u - 386,  isf32);
      else if (u < 578) v = ldf(b_emb,  u - 514,  isf32);
      else if (u < 770) v = ldf(b_ih,   u - 578,  isf32);
      else if (u < 962) v = ldf(b_hh,   u - 770,  isf32);
      else              v = isf32 ? 1.0f : 0.0f;
      smallf[u] = v;
    }
  }
}

__global__ __launch_bounds__(256) void pair_kernel(
    const float* __restrict__ smallf,
    const unsigned short* __restrict__ Wp_bf,
    const float* __restrict__ WTf,
    const float* __restrict__ last_in,
    float* __restrict__ last_out,
    const unsigned short* __restrict__ hbf_in,
    unsigned short* __restrict__ hbf_out,
    float* __restrict__ h_carry,
    void* __restrict__ out,
    int t)
{
  const int i    = blockIdx.x;
  const int tid  = threadIdx.x;
  const int lane = tid & 63;
  const int wave = tid >> 6;
  const int col  = lane & 15;
  const int quad = lane >> 4;

  __shared__ float red[4][64];

  const float2* lp = (const float2*)last_in;
  const float2  li = lp[i];

  float wr0[2][8], wr1[2][8], brl[2][8];
  #pragma unroll
  for (int ks = 0; ks < 2; ++ks) {
    int kb = ks * 32 + quad * 8;
    #pragma unroll
    for (int j = 0; j < 8; ++j) {
      wr0[ks][j] = smallf[OFF_WREL + kb + j];
      wr1[ks][j] = smallf[OFF_WREL + 64 + kb + j];
      brl[ks][j] = smallf[OFF_BREL + kb + j];
    }
  }
  float bp[4];
  #pragma unroll
  for (int nt = 0; nt < 4; ++nt) bp[nt] = smallf[OFF_BPOOL + nt * 16 + col];

  FragU bw[4][4];
  #pragma unroll
  for (int nt = 0; nt < 4; ++nt)
    #pragma unroll
    for (int ks = 0; ks < 4; ++ks)
      #pragma unroll
      for (int j = 0; j < 8; ++j)
        bw[nt][ks].u[j] = Wp_bf[(ks * 32 + quad * 8 + j) * 64 + nt * 16 + col];

  float vmax[4] = {0.f, 0.f, 0.f, 0.f};

  const int jb0 = wave * 128;
  for (int s = 0; s < 4; ++s) {
    const int jb = jb0 + s * 32;
    const int r0 = jb + col, r1 = r0 + 16;
    const float2 l0 = lp[r0], l1 = lp[r1];
    const float d0x = l0.x - li.x, d0y = l0.y - li.y;
    const float d1x = l1.x - li.x, d1y = l1.y - li.y;

    FragU aE[2][2];
    #pragma unroll
    for (int ks = 0; ks < 2; ++ks) {
      #pragma unroll
      for (int j = 0; j < 8; ++j) {
        float e0 = fmaxf(d0x * wr0[ks][j] + d0y * wr1[ks][j] + brl[ks][j], 0.f);
        float e1 = fmaxf(d1x * wr0[ks][j] + d1y * wr1[ks][j] + brl[ks][j], 0.f);
        aE[0][ks].u[j] = f2bf(e0);
        aE[1][ks].u[j] = f2bf(e1);
      }
    }
    bf16x8 aH[2][2];
    #pragma unroll
    for (int mt = 0; mt < 2; ++mt) {
      int jr = jb + mt * 16 + col;
      #pragma unroll
      for (int ks = 0; ks < 2; ++ks)
        aH[mt][ks] = *(const bf16x8*)(hbf_in + jr * 64 + ks * 32 + quad * 8);
    }

    f32x4 acc[2][4];
    #pragma unroll
    for (int mt = 0; mt < 2; ++mt)
      #pragma unroll
      for (int nt = 0; nt < 4; ++nt)
        acc[mt][nt] = (f32x4){0.f, 0.f, 0.f, 0.f};

    #pragma unroll
    for (int nt = 0; nt < 4; ++nt)
      #pragma unroll
      for (int mt = 0; mt < 2; ++mt) {
        acc[mt][nt] = __builtin_amdgcn_mfma_f32_16x16x32_bf16(aE[mt][0].v, bw[nt][0].v, acc[mt][nt], 0, 0, 0);
        acc[mt][nt] = __builtin_amdgcn_mfma_f32_16x16x32_bf16(aE[mt][1].v, bw[nt][1].v, acc[mt][nt], 0, 0, 0);
        acc[mt][nt] = __builtin_amdgcn_mfma_f32_16x16x32_bf16(aH[mt][0],   bw[nt][2].v, acc[mt][nt], 0, 0, 0);
        acc[mt][nt] = __builtin_amdgcn_mfma_f32_16x16x32_bf16(aH[mt][1],   bw[nt][3].v, acc[mt][nt], 0, 0, 0);
      }

    #pragma unroll
    for (int mt = 0; mt < 2; ++mt)
      #pragma unroll
      for (int nt = 0; nt < 4; ++nt)
        #pragma unroll
        for (int r = 0; r < 4; ++r) {
          float v = acc[mt][nt][r] + bp[nt];
          vmax[nt] = fmaxf(fmaxf(v, 0.f), vmax[nt]);
        }
  }

  #pragma unroll
  for (int nt = 0; nt < 4; ++nt) {
    vmax[nt] = fmaxf(vmax[nt], __shfl_xor(vmax[nt], 16, 64));
    vmax[nt] = fmaxf(vmax[nt], __shfl_xor(vmax[nt], 32, 64));
  }
  if (lane < 16) {
    #pragma unroll
    for (int nt = 0; nt < 4; ++nt) red[wave][nt * 16 + lane] = vmax[nt];
  }
  __syncthreads();

  if (tid < 64) {
    const int o = tid;
    const bool isf32 = (smallf[OFF_FLAG] != 0.0f);
    float pooled = fmaxf(fmaxf(red[0][o], red[1][o]), fmaxf(red[2][o], red[3][o]));
    float p0 = pooled * smallf[OFF_WPOS + o * 2 + 0];
    float p1 = pooled * smallf[OFF_WPOS + o * 2 + 1];
    #pragma unroll
    for (int sft = 32; sft >= 1; sft >>= 1) {
      p0 += __shfl_xor(p0, sft, 64);
      p1 += __shfl_xor(p1, sft, 64);
    }
    p0 += smallf[OFF_BPOS + 0];
    p1 += smallf[OFF_BPOS + 1];
    if (o == 0) {
      stout(out, i * 40 + (OBS + t) * 2 + 0, p0, isf32);
      stout(out, i * 40 + (OBS + t) * 2 + 1, p1, isf32);
      last_out[2 * i]     = p0;
      last_out[2 * i + 1] = p1;
    }
    float gir = 0.f, giz = 0.f, gin = 0.f, ghr = 0.f, ghz = 0.f, ghn = 0.f;
    #pragma unroll 8
    for (int k = 0; k < 64; ++k) {
      float ek = p0 * smallf[OFF_WEMB + k] + p1 * smallf[OFF_WEMB + 64 + k]
               + smallf[OFF_BEMB + k];
      float hk = h_carry[i * 64 + k];
      const float* w = WTf + k * 384;
      gir += ek * w[o];
      giz += ek * w[64 + o];
      gin += ek * w[128 + o];
      ghr += hk * w[192 + o];
      ghz += hk * w[256 + o];
      ghn += hk * w[320 + o];
    }
    gir += smallf[OFF_BIH + o];       ghr += smallf[OFF_BHH + o];
    giz += smallf[OFF_BIH + 64 + o];  ghz += smallf[OFF_BHH + 64 + o];
    gin += smallf[OFF_BIH + 128 + o]; ghn += smallf[OFF_BHH + 128 + o];
    float r = 1.f / (1.f + __expf(-(gir + ghr)));
    float z = 1.f / (1.f + __expf(-(giz + ghz)));
    float n = tanhf(gin + r * ghn);
    float hp = h_carry[i * 64 + o];
    float hn = (1.f - z) * n + z * hp;
    h_carry[i * 64 + o] = hn;
    hbf_out[i * 64 + o] = f2bf(hn);
  }
}

// ---------------------------------------------------------------------------
extern "C" void kernel_launch(void* const* d_in, const int* in_sizes, int n_in,
                              void* d_out, int out_size, void* d_ws, size_t ws_size,
                              hipStream_t stream) {
  (void)in_sizes; (void)n_in; (void)out_size;
  const void* hidden_state = d_in[0];
  const void* group_track  = d_in[1];
  const void* W_emb  = d_in[2];
  const void* b_emb  = d_in[3];
  const void* W_ih   = d_in[4];
  const void* W_hh   = d_in[5];
  const void* b_ih   = d_in[6];
  const void* b_hh   = d_in[7];
  const void* W_pos  = d_in[8];
  const void* b_pos  = d_in[9];
  const void* W_rel  = d_in[10];
  const void* b_rel  = d_in[11];
  const void* W_pool = d_in[12];
  const void* b_pool = d_in[13];

  char* ws = (char*)d_ws;

  if (ws_size >= WS_TOTAL) {
    unsigned*       bar      = (unsigned*)(ws + WS_BAR);
    float*          smallf   = (float*)(ws + WS_SMALL);
    float*          WTf      = (float*)(ws + WS_WTF);
    unsigned short* Wp_bf    = (unsigned short*)(ws + WS_WPBF);
    float2*         lastbase = (float2*)(ws + WS_LAST);
    unsigned short* hbfbase  = (unsigned short*)(ws + WS_HBF);

    init_kernel<<<1, 128, 0, stream>>>(bar);
    fused_kernel<<<NBLK, 1024, 0, stream>>>(hidden_state, group_track,
                                            W_emb, b_emb, W_ih, W_hh, b_ih, b_hh,
                                            W_pos, b_pos, W_rel, b_rel,
                                            W_pool, b_pool,
                                            lastbase, hbfbase,
                                            WTf, Wp_bf, smallf, bar, d_out);
    return;
  }

  // ---- fallback: known-good 13-launch path, old compact layout ----
  float* lastA            = (float*)(ws + 0);
  float* lastB            = (float*)(ws + 4096);
  unsigned short* hbfA    = (unsigned short*)(ws + 8192);
  unsigned short* hbfB    = (unsigned short*)(ws + 73728);
  float* h_carry          = (float*)(ws + 139264);
  float* WTf              = (float*)(ws + 270336);
  unsigned short* Wp_bf   = (unsigned short*)(ws + 368640);
  float* smallf           = (float*)(ws + 385024);

  prep_kernel<<<512, 64, 0, stream>>>(hidden_state, group_track,
                                      W_emb, b_emb, W_ih, W_hh, b_ih, b_hh,
                                      W_pos, b_pos, W_rel, b_rel, W_pool, b_pool,
                                      lastA, hbfA, h_carry, WTf, Wp_bf,
                                      smallf, d_out);
  float* lastBuf[2] = {lastA, lastB};
  unsigned short* hbfBuf[2] = {hbfA, hbfB};
  for (int t = 0; t < PRE; ++t) {
    int p = t & 1;
    pair_kernel<<<512, 256, 0, stream>>>(smallf, Wp_bf, WTf,
                                         lastBuf[p], lastBuf[1 - p],
                                         hbfBuf[p], hbfBuf[1 - p],
                                         h_carry, d_out, t);
  }
}

// Round 8
// 262.169 us; speedup vs baseline: 2.9391x; 2.9391x over previous
//
#include <hip/hip_runtime.h>
#include <math.h>

// Problem constants
#define NB   512   // B (agents)
#define NBLK 256   // fused-path blocks (2 agents per block)
#define NH   64    // H = E = HP
#define OBS  8
#define PRE  12

// small f32 param pack offsets (elements)
#define OFF_WREL  0     // 128
#define OFF_BREL  128   // 64
#define OFF_BPOOL 192   // 64
#define OFF_WPOS  256   // 128
#define OFF_BPOS  384   // 2
#define OFF_WEMB  386   // 128
#define OFF_BEMB  514   // 64
#define OFF_BIH   578   // 192
#define OFF_BHH   770   // 192
#define OFF_FLAG  962   // 1: 1.0 if buffers are f32, 0.0 if bf16
#define N_SMALL   963

// ---- fused-path workspace layout (page-gapped write-once buffers) ----------
#define WS_BAR    0         // 4096 B (barrier counters, zeroed by init_kernel)
#define WS_SMALL  4096      // 4096 B (963 f32 used)
#define WS_WTF    8192      // 98304 B
#define WS_WPBF   106496    // 16384 B
#define WS_LAST   122880    // 13 * 8192 B   (4 KB data + 4 KB page gap each)
#define WS_HBF    229376    // 13 * 69632 B  (64 KB data + 4 KB page gap each)
#define WS_TOTAL  1134592
#define LAST_STRIDE_F2  1024   // float2 elems per last buffer slot
#define HBF_STRIDE_U16  34816  // u16 elems per hbf buffer slot

typedef __bf16 bf16x8 __attribute__((ext_vector_type(8)));
typedef float  f32x4  __attribute__((ext_vector_type(4)));

union FragU { bf16x8 v; unsigned short u[8]; };

__device__ __forceinline__ float bf2f(unsigned short u) {
  unsigned int x = ((unsigned int)u) << 16;
  return __builtin_bit_cast(float, x);
}
__device__ __forceinline__ unsigned short f2bf(float f) {
  unsigned int u = __builtin_bit_cast(unsigned int, f);
  u += 0x7FFFu + ((u >> 16) & 1u);   // RNE
  return (unsigned short)(u >> 16);
}
__device__ __forceinline__ float ldf(const void* p, int i, bool isf32) {
  return isf32 ? ((const float*)p)[i] : bf2f(((const unsigned short*)p)[i]);
}
__device__ __forceinline__ unsigned short ld16(const void* p, int i, bool isf32) {
  return isf32 ? f2bf(((const float*)p)[i]) : ((const unsigned short*)p)[i];
}
__device__ __forceinline__ void stout(void* p, int i, float v, bool isf32) {
  if (isf32) ((float*)p)[i] = v;
  else       ((unsigned short*)p)[i] = f2bf(v);
}

// ---- device-coherent stores: write-through to the IC coherence point so
// consumers on other XCDs see fresh data on their (plain, cached) first touch.
__device__ __forceinline__ void st32_sc(unsigned* p, unsigned v) {
  __hip_atomic_store(p, v, __ATOMIC_RELAXED, __HIP_MEMORY_SCOPE_AGENT);
}
__device__ __forceinline__ void stf_sc(float* p, float v) {
  __hip_atomic_store(p, v, __ATOMIC_RELAXED, __HIP_MEMORY_SCOPE_AGENT);
}
__device__ __forceinline__ void st64_sc(void* p, unsigned long long v) {
  __hip_atomic_store((unsigned long long*)p, v, __ATOMIC_RELAXED, __HIP_MEMORY_SCOPE_AGENT);
}

// ---- 2-level tree barrier in workspace for NBLK=256 blocks.
// bar[0..15]=leaf (16 blocks each), bar[64]=root, bar[96]=release (rounds).
// Counters monotonic; init_kernel zeroes. __syncthreads() at entry drains all
// waves' vm ops; the explicit vmcnt(0) covers the arriving thread itself.
// Ran correctly at 256 blocks in round 6.
// ---------------------------------------------------------------------------
__device__ __forceinline__ void grid_barrier(unsigned* bar, unsigned phase,
                                             int tid, int bid) {
  __syncthreads();
  if (tid == 0) {
    asm volatile("s_waitcnt vmcnt(0)" ::: "memory");
    unsigned prev = __hip_atomic_fetch_add(&bar[bid & 15], 1u,
                                           __ATOMIC_RELAXED, __HIP_MEMORY_SCOPE_AGENT);
    if ((prev & 15u) == 15u) {
      unsigned r = __hip_atomic_fetch_add(&bar[64], 1u,
                                          __ATOMIC_RELAXED, __HIP_MEMORY_SCOPE_AGENT);
      if ((r & 15u) == 15u) {
        __hip_atomic_store(&bar[96], (r >> 4) + 1u,
                           __ATOMIC_RELAXED, __HIP_MEMORY_SCOPE_AGENT);
      }
    }
    while (__hip_atomic_load(&bar[96], __ATOMIC_RELAXED,
                             __HIP_MEMORY_SCOPE_AGENT) < phase)
      __builtin_amdgcn_s_sleep(2);
  }
  __syncthreads();
}

__global__ __launch_bounds__(128) void init_kernel(unsigned* bar) {
  bar[threadIdx.x] = 0;
}

// ---------------------------------------------------------------------------
// FUSED persistent kernel: prep + all 12 decoder steps. 256 blocks x 512
// threads (8 waves), TWO agents per block (waves 0-3 -> agent 2*bid,
// waves 4-7 -> agent 2*bid+1).
// RESIDENCY-SLACK RULE (from rounds 5/7 failures vs 4/6 successes): the
// spin barrier needs capacity >= 2x block count, not exact fit. Here:
// __launch_bounds__(512,2) caps VGPR at 128 (rounds 2/4-verified zero-spill
// budget); at 128 VGPR a CU hosts 16 waves = 2 of these blocks -> 512 slots
// for 256 blocks = 2x slack. Rounds 5/7 (512 blocks, 2/CU) were exact-fit
// and hung. When balanced: 16 waves/CU = 2x round 4's latency hiding.
// Per-agent inner code is byte-wise round 4's proven 4-wave structure;
// 2-agent packing is byte-wise round 6's proven indexing.
// ---------------------------------------------------------------------------
__global__ __launch_bounds__(512, 2) void fused_kernel(
    const void* __restrict__ hidden_state, // (1,512,64)
    const void* __restrict__ group_track,  // (512,8,2)
    const void* __restrict__ W_emb,  const void* __restrict__ b_emb,
    const void* __restrict__ W_ih,   const void* __restrict__ W_hh,
    const void* __restrict__ b_ih,   const void* __restrict__ b_hh,
    const void* __restrict__ W_pos,  const void* __restrict__ b_pos,
    const void* __restrict__ W_rel,  const void* __restrict__ b_rel,
    const void* __restrict__ W_pool, const void* __restrict__ b_pool,
    float2* __restrict__ lastbase,         // 13 slots, stride LAST_STRIDE_F2
    unsigned short* __restrict__ hbfbase,  // 13 slots, stride HBF_STRIDE_U16
    float* __restrict__ WTf,               // (64,384) f32 transposed GRU W
    unsigned short* __restrict__ Wp_bf,    // (128,64) bf16 W_pool
    float* __restrict__ smallf,            // N_SMALL f32 param pack
    unsigned* __restrict__ bar,            // barrier counters (zeroed)
    void* __restrict__ out)                // (512,20,2) dtype = input dtype
{
  const int bid  = blockIdx.x;
  const int tid  = threadIdx.x;   // 0..511
  const int lane = tid & 63;
  const int wave = tid >> 6;      // 0..7
  const int ag   = wave >> 2;     // 0..1  (agent slot within block)
  const int wv   = wave & 3;      // 0..3  (wave within agent)
  const int i    = 2 * bid + ag;  // global agent id
  const int col  = lane & 15;     // MFMA m (A rows) / n (B cols) index
  const int quad = lane >> 4;     // selects k-group (quad*8 .. quad*8+7)

  __shared__ float  red[2][4][64];
  __shared__ float  part[2][4][6][64];
  __shared__ float  hstate[2][64];       // per-agent f32 GRU carry
  __shared__ float2 lpos[512];           // per-step staged last positions

  // ======================= prep ==========================
  // dtype detect: bf16-interpret first 256 u16 of hidden_state. Identical
  // wave-uniform result in every wave.
  int bad = 0;
  const unsigned short* hs16 = (const unsigned short*)hidden_state;
  for (int k = lane; k < 256; k += 64) {
    unsigned e = (hs16[k] >> 7) & 0xFFu;
    bad |= (e >= 0x8Eu) ? 1 : 0;
  }
  const bool isf32 = (__ballot(bad) != 0ULL);

  if (tid < 64) {                      // both agents' h0 rows -> bf16 u32, sc
    int a2 = tid >> 5, w32 = tid & 31;
    int ii = 2 * bid + a2;
    unsigned lo = ld16(hidden_state, ii * 64 + 2 * w32,     isf32);
    unsigned hi = ld16(hidden_state, ii * 64 + 2 * w32 + 1, isf32);
    st32_sc((unsigned*)hbfbase + ii * 32 + w32, lo | (hi << 16));
  }
  if (tid < 128) hstate[tid >> 6][tid & 63] = 0.0f;
  if (tid < 32) {                      // observed track -> out, both agents
    int a2 = tid >> 4, k = tid & 15;
    int ii = 2 * bid + a2;
    stout(out, ii * 40 + k, ldf(group_track, ii * 16 + k, isf32), isf32);
  }
  if (tid < 2) {                       // last0, both agents
    int ii = 2 * bid + tid;
    float2 l0;
    l0.x = ldf(group_track, ii * 16 + 14, isf32);
    l0.y = ldf(group_track, ii * 16 + 15, isf32);
    st64_sc(lastbase + ii, __builtin_bit_cast(unsigned long long, l0));
  }

  if (bid < 48) {                      // WTf: 24576 elems = 48 blocks x 512
    int u = bid * 512 + tid;
    int k = u / 384, c = u % 384;
    float v = (c < 192) ? ldf(W_ih, c * 64 + k, isf32)
                        : ldf(W_hh, (c - 192) * 64 + k, isf32);
    stf_sc(&WTf[u], v);
  } else if (bid < 56) {               // Wp_bf: 4096 u32 = 8 blocks x 512
    int u = (bid - 48) * 512 + tid;
    unsigned lo = ld16(W_pool, 2 * u,     isf32);
    unsigned hi = ld16(W_pool, 2 * u + 1, isf32);
    st32_sc((unsigned*)Wp_bf + u, lo | (hi << 16));
  } else if (bid >= 128 && bid < 130) {  // smallf pack: 963 elems = 2 x 512
    int u = (bid - 128) * 512 + tid;
    if (u < N_SMALL) {
      float v;
      if      (u < 128) v = ldf(W_rel,  u,        isf32);
      else if (u < 192) v = ldf(b_rel,  u - 128,  isf32);
      else if (u < 256) v = ldf(b_pool, u - 192,  isf32);
      else if (u < 384) v = ldf(W_pos,  u - 256,  isf32);
      else if (u < 386) v = ldf(b_pos,  u - 384,  isf32);
      else if (u < 514) v = ldf(W_emb,  u - 386,  isf32);
      else if (u < 578) v = ldf(b_emb,  u - 514,  isf32);
      else if (u < 770) v = ldf(b_ih,   u - 578,  isf32);
      else if (u < 962) v = ldf(b_hh,   u - 770,  isf32);
      else              v = isf32 ? 1.0f : 0.0f;   // OFF_FLAG
      stf_sc(&smallf[u], v);
    }
  }
  grid_barrier(bar, 1u, tid, bid);

  // =================== persistent per-lane fragments =======================
  // Write-once data: plain cached loads, first touch is after the barrier.
  float wr0[2][8], wr1[2][8], brl[2][8];
  #pragma unroll
  for (int ks = 0; ks < 2; ++ks) {
    int kb = ks * 32 + quad * 8;
    #pragma unroll
    for (int j = 0; j < 8; ++j) {
      wr0[ks][j] = smallf[OFF_WREL + kb + j];
      wr1[ks][j] = smallf[OFF_WREL + 64 + kb + j];
      brl[ks][j] = smallf[OFF_BREL + kb + j];
    }
  }
  float bp[4];
  #pragma unroll
  for (int nt = 0; nt < 4; ++nt) bp[nt] = smallf[OFF_BPOOL + nt * 16 + col];

  // B-operand fragments of full W_pool (K=128): lane holds
  // B[k = ks*32 + quad*8 + j][n = nt*16 + col]
  FragU bw[4][4];
  #pragma unroll
  for (int nt = 0; nt < 4; ++nt)
    #pragma unroll
    for (int ks = 0; ks < 4; ++ks)
      #pragma unroll
      for (int j = 0; j < 8; ++j)
        bw[nt][ks].u[j] = Wp_bf[(ks * 32 + quad * 8 + j) * 64 + nt * 16 + col];

  // ========================== decode loop ==================================
  for (int t = 0; t < PRE; ++t) {
    // step-t buffers are ready (barrier passed); all loads below are plain.
    const float2*         lp       = lastbase + t * LAST_STRIDE_F2;
    float2*               last_out = lastbase + (t + 1) * LAST_STRIDE_F2;
    const unsigned short* hbf_in   = hbfbase + t * HBF_STRIDE_U16;
    unsigned short*       hbf_out  = hbfbase + (t + 1) * HBF_STRIDE_U16;

    lpos[tid] = lp[tid];               // stage all 512 positions in LDS
    __syncthreads();
    const float2 li = lpos[i];

    float vmax[4] = {0.f, 0.f, 0.f, 0.f};  // m = relu(..) >= 0, so 0 is safe

    // --- j loop: this wave covers rows [wv*128, wv*128+128), 32 at a time
    const int jb0 = wv * 128;
    for (int s = 0; s < 4; ++s) {
      const int jb = jb0 + s * 32;
      const int r0 = jb + col, r1 = r0 + 16;
      const float2 l0 = lpos[r0], l1 = lpos[r1];
      const float d0x = l0.x - li.x, d0y = l0.y - li.y;
      const float d1x = l1.x - li.x, d1y = l1.y - li.y;

      // A-fragments for e-part (K rows 0..63)
      FragU aE[2][2];
      #pragma unroll
      for (int ks = 0; ks < 2; ++ks) {
        #pragma unroll
        for (int j = 0; j < 8; ++j) {
          float e0 = fmaxf(d0x * wr0[ks][j] + d0y * wr1[ks][j] + brl[ks][j], 0.f);
          float e1 = fmaxf(d1x * wr0[ks][j] + d1y * wr1[ks][j] + brl[ks][j], 0.f);
          aE[0][ks].u[j] = f2bf(e0);
          aE[1][ks].u[j] = f2bf(e1);
        }
      }
      // A-fragments for h-part (K rows 64..127): plain 16B vector loads
      bf16x8 aH[2][2];
      #pragma unroll
      for (int mt = 0; mt < 2; ++mt) {
        int jr = jb + mt * 16 + col;
        #pragma unroll
        for (int ks = 0; ks < 2; ++ks)
          aH[mt][ks] = *(const bf16x8*)(hbf_in + jr * 64 + ks * 32 + quad * 8);
      }

      f32x4 acc[2][4];
      #pragma unroll
      for (int mt = 0; mt < 2; ++mt)
        #pragma unroll
        for (int nt = 0; nt < 4; ++nt)
          acc[mt][nt] = (f32x4){0.f, 0.f, 0.f, 0.f};

      #pragma unroll
      for (int nt = 0; nt < 4; ++nt)
        #pragma unroll
        for (int mt = 0; mt < 2; ++mt) {
          acc[mt][nt] = __builtin_amdgcn_mfma_f32_16x16x32_bf16(aE[mt][0].v, bw[nt][0].v, acc[mt][nt], 0, 0, 0);
          acc[mt][nt] = __builtin_amdgcn_mfma_f32_16x16x32_bf16(aE[mt][1].v, bw[nt][1].v, acc[mt][nt], 0, 0, 0);
          acc[mt][nt] = __builtin_amdgcn_mfma_f32_16x16x32_bf16(aH[mt][0],   bw[nt][2].v, acc[mt][nt], 0, 0, 0);
          acc[mt][nt] = __builtin_amdgcn_mfma_f32_16x16x32_bf16(aH[mt][1],   bw[nt][3].v, acc[mt][nt], 0, 0, 0);
        }

      // epilogue: + b_pool, relu, running max over rows (fuses to v_max3)
      #pragma unroll
      for (int mt = 0; mt < 2; ++mt)
        #pragma unroll
        for (int nt = 0; nt < 4; ++nt)
          #pragma unroll
          for (int r = 0; r < 4; ++r) {
            float v = acc[mt][nt][r] + bp[nt];
            vmax[nt] = fmaxf(fmaxf(v, 0.f), vmax[nt]);
          }
    }

    // reduce over quads within the wave, publish per-wave max
    #pragma unroll
    for (int nt = 0; nt < 4; ++nt) {
      vmax[nt] = fmaxf(vmax[nt], __shfl_xor(vmax[nt], 16, 64));
      vmax[nt] = fmaxf(vmax[nt], __shfl_xor(vmax[nt], 32, 64));
    }
    if (lane < 16) {
      #pragma unroll
      for (int nt = 0; nt < 4; ++nt) red[ag][wv][nt * 16 + lane] = vmax[nt];
    }
    __syncthreads();   // sync1: red[] complete; hstate stable from prev step

    // ---------- head: pos -> emb -> GRU, 4-way wave-parallel per agent -----
    {
      const int o = lane;
      float pooled = fmaxf(fmaxf(red[ag][0][o], red[ag][1][o]),
                           fmaxf(red[ag][2][o], red[ag][3][o]));
      float p0 = pooled * smallf[OFF_WPOS + o * 2 + 0];
      float p1 = pooled * smallf[OFF_WPOS + o * 2 + 1];
      #pragma unroll
      for (int sft = 32; sft >= 1; sft >>= 1) {
        p0 += __shfl_xor(p0, sft, 64);
        p1 += __shfl_xor(p1, sft, 64);
      }
      p0 += smallf[OFF_BPOS + 0];
      p1 += smallf[OFF_BPOS + 1];

      // wave wv accumulates k in [16wv, 16wv+16): partial 6 gate mat-vecs
      float g0 = 0.f, g1 = 0.f, g2 = 0.f, g3 = 0.f, g4 = 0.f, g5 = 0.f;
      #pragma unroll 8
      for (int kk = 0; kk < 16; ++kk) {
        int k = wv * 16 + kk;
        float ek = p0 * smallf[OFF_WEMB + k] + p1 * smallf[OFF_WEMB + 64 + k]
                 + smallf[OFF_BEMB + k];          // emb_k (uniform)
        float hk = hstate[ag][k];                 // uniform LDS broadcast
        const float* w = WTf + k * 384;           // coalesced across lanes
        g0 += ek * w[o];
        g1 += ek * w[64 + o];
        g2 += ek * w[128 + o];
        g3 += hk * w[192 + o];
        g4 += hk * w[256 + o];
        g5 += hk * w[320 + o];
      }
      part[ag][wv][0][o] = g0; part[ag][wv][1][o] = g1; part[ag][wv][2][o] = g2;
      part[ag][wv][3][o] = g3; part[ag][wv][4][o] = g4; part[ag][wv][5][o] = g5;
      __syncthreads();   // sync2: partials complete; hstate reads done

      if (wv == 0) {     // waves 0 and 4: one finisher wave per agent
        float gir = 0.f, giz = 0.f, gin = 0.f, ghr = 0.f, ghz = 0.f, ghn = 0.f;
        #pragma unroll
        for (int pp = 0; pp < 4; ++pp) {
          gir += part[ag][pp][0][o]; giz += part[ag][pp][1][o]; gin += part[ag][pp][2][o];
          ghr += part[ag][pp][3][o]; ghz += part[ag][pp][4][o]; ghn += part[ag][pp][5][o];
        }
        gir += smallf[OFF_BIH + o];       ghr += smallf[OFF_BHH + o];
        giz += smallf[OFF_BIH + 64 + o];  ghz += smallf[OFF_BHH + 64 + o];
        gin += smallf[OFF_BIH + 128 + o]; ghn += smallf[OFF_BHH + 128 + o];
        float r = 1.f / (1.f + __expf(-(gir + ghr)));
        float z = 1.f / (1.f + __expf(-(giz + ghz)));
        float n = tanhf(gin + r * ghn);
        float hp = hstate[ag][o];
        float hn = (1.f - z) * n + z * hp;
        hstate[ag][o] = hn;                  // safe: all reads were pre-sync2
        // pack bf16 pairs, sc-store as u32 into next step's write-once buf
        int hbi = (int)f2bf(hn);
        unsigned v0 = (unsigned)__shfl(hbi, (o & 31) * 2, 64);
        unsigned v1 = (unsigned)__shfl(hbi, (o & 31) * 2 + 1, 64);
        if (o < 32)
          st32_sc((unsigned*)hbf_out + i * 32 + o, v0 | (v1 << 16));
        if (o == 0) {
          stout(out, i * 40 + (OBS + t) * 2 + 0, p0, isf32);
          stout(out, i * 40 + (OBS + t) * 2 + 1, p1, isf32);
          float2 pr; pr.x = p0; pr.y = p1;
          st64_sc(last_out + i, __builtin_bit_cast(unsigned long long, pr));
        }
      }
    }

    if (t < PRE - 1) grid_barrier(bar, (unsigned)(t + 2), tid, bid);
  }
}

// ---------------------------------------------------------------------------
// FALLBACK path (known-good 13-launch version) if workspace is too small.
// Uses its own (old) compact workspace layout.
// ---------------------------------------------------------------------------
__global__ __launch_bounds__(64) void prep_kernel(
    const void* __restrict__ hidden_state,
    const void* __restrict__ group_track,
    const void* __restrict__ W_emb,  const void* __restrict__ b_emb,
    const void* __restrict__ W_ih,   const void* __restrict__ W_hh,
    const void* __restrict__ b_ih,   const void* __restrict__ b_hh,
    const void* __restrict__ W_pos,  const void* __restrict__ b_pos,
    const void* __restrict__ W_rel,  const void* __restrict__ b_rel,
    const void* __restrict__ W_pool, const void* __restrict__ b_pool,
    float* __restrict__ last0,
    unsigned short* __restrict__ hbf0,
    float* __restrict__ h_carry,
    float* __restrict__ WTf,
    unsigned short* __restrict__ Wp_bf,
    float* __restrict__ smallf,
    void* __restrict__ out)
{
  const int b = blockIdx.x;
  const int o = threadIdx.x;

  int bad = 0;
  const unsigned short* hs16 = (const unsigned short*)hidden_state;
  for (int k = o; k < 256; k += 64) {
    unsigned e = (hs16[k] >> 7) & 0xFFu;
    bad |= (e >= 0x8Eu) ? 1 : 0;
  }
  const bool isf32 = (__ballot(bad) != 0ULL);

  hbf0[b * 64 + o] = ld16(hidden_state, b * 64 + o, isf32);
  h_carry[b * 64 + o] = 0.0f;
  if (o < 16) stout(out, b * 40 + o, ldf(group_track, b * 16 + o, isf32), isf32);
  if (o < 2)  last0[b * 2 + o] = ldf(group_track, b * 16 + 14 + o, isf32);

  if (b < 384) {
    int u = b * 64 + o;
    int k = u / 384, c = u % 384;
    WTf[u] = (c < 192) ? ldf(W_ih, c * 64 + k, isf32)
                       : ldf(W_hh, (c - 192) * 64 + k, isf32);
  } else {
    int u = (b - 384) * 64 + o;
    Wp_bf[u] = ld16(W_pool, u, isf32);
  }

  if (b < 16) {
    int u = b * 64 + o;
    if (u < N_SMALL) {
      float v;
      if      (u < 128) v = ldf(W_rel,  u,        isf32);
      else if (u < 192) v = ldf(b_rel,  u - 128,  isf32);
      else if (u < 256) v = ldf(b_pool, u - 192,  isf32);
      else if (u < 384) v = ldf(W_pos,  u - 256,  isf32);
      else if (u < 386) v = ldf(b_pos,  u - 384,  isf32);
      else if (u < 514) v = ldf(W_emb,  u - 386,  isf32);
      else if (u < 578) v = ldf(b_emb,  u - 514,  isf32);
      else if (u < 770) v = ldf(b_ih,   u - 578,  isf32);
      else if (u < 962) v = ldf(b_hh,   u - 770,  isf32);
      else              v = isf32 ? 1.0f : 0.0f;
      smallf[u] = v;
    }
  }
}

__global__ __launch_bounds__(256) void pair_kernel(
    const float* __restrict__ smallf,
    const unsigned short* __restrict__ Wp_bf,
    const float* __restrict__ WTf,
    const float* __restrict__ last_in,
    float* __restrict__ last_out,
    const unsigned short* __restrict__ hbf_in,
    unsigned short* __restrict__ hbf_out,
    float* __restrict__ h_carry,
    void* __restrict__ out,
    int t)
{
  const int i    = blockIdx.x;
  const int tid  = threadIdx.x;
  const int lane = tid & 63;
  const int wave = tid >> 6;
  const int col  = lane & 15;
  const int quad = lane >> 4;

  __shared__ float red[4][64];

  const float2* lp = (const float2*)last_in;
  const float2  li = lp[i];

  float wr0[2][8], wr1[2][8], brl[2][8];
  #pragma unroll
  for (int ks = 0; ks < 2; ++ks) {
    int kb = ks * 32 + quad * 8;
    #pragma unroll
    for (int j = 0; j < 8; ++j) {
      wr0[ks][j] = smallf[OFF_WREL + kb + j];
      wr1[ks][j] = smallf[OFF_WREL + 64 + kb + j];
      brl[ks][j] = smallf[OFF_BREL + kb + j];
    }
  }
  float bp[4];
  #pragma unroll
  for (int nt = 0; nt < 4; ++nt) bp[nt] = smallf[OFF_BPOOL + nt * 16 + col];

  FragU bw[4][4];
  #pragma unroll
  for (int nt = 0; nt < 4; ++nt)
    #pragma unroll
    for (int ks = 0; ks < 4; ++ks)
      #pragma unroll
      for (int j = 0; j < 8; ++j)
        bw[nt][ks].u[j] = Wp_bf[(ks * 32 + quad * 8 + j) * 64 + nt * 16 + col];

  float vmax[4] = {0.f, 0.f, 0.f, 0.f};

  const int jb0 = wave * 128;
  for (int s = 0; s < 4; ++s) {
    const int jb = jb0 + s * 32;
    const int r0 = jb + col, r1 = r0 + 16;
    const float2 l0 = lp[r0], l1 = lp[r1];
    const float d0x = l0.x - li.x, d0y = l0.y - li.y;
    const float d1x = l1.x - li.x, d1y = l1.y - li.y;

    FragU aE[2][2];
    #pragma unroll
    for (int ks = 0; ks < 2; ++ks) {
      #pragma unroll
      for (int j = 0; j < 8; ++j) {
        float e0 = fmaxf(d0x * wr0[ks][j] + d0y * wr1[ks][j] + brl[ks][j], 0.f);
        float e1 = fmaxf(d1x * wr0[ks][j] + d1y * wr1[ks][j] + brl[ks][j], 0.f);
        aE[0][ks].u[j] = f2bf(e0);
        aE[1][ks].u[j] = f2bf(e1);
      }
    }
    bf16x8 aH[2][2];
    #pragma unroll
    for (int mt = 0; mt < 2; ++mt) {
      int jr = jb + mt * 16 + col;
      #pragma unroll
      for (int ks = 0; ks < 2; ++ks)
        aH[mt][ks] = *(const bf16x8*)(hbf_in + jr * 64 + ks * 32 + quad * 8);
    }

    f32x4 acc[2][4];
    #pragma unroll
    for (int mt = 0; mt < 2; ++mt)
      #pragma unroll
      for (int nt = 0; nt < 4; ++nt)
        acc[mt][nt] = (f32x4){0.f, 0.f, 0.f, 0.f};

    #pragma unroll
    for (int nt = 0; nt < 4; ++nt)
      #pragma unroll
      for (int mt = 0; mt < 2; ++mt) {
        acc[mt][nt] = __builtin_amdgcn_mfma_f32_16x16x32_bf16(aE[mt][0].v, bw[nt][0].v, acc[mt][nt], 0, 0, 0);
        acc[mt][nt] = __builtin_amdgcn_mfma_f32_16x16x32_bf16(aE[mt][1].v, bw[nt][1].v, acc[mt][nt], 0, 0, 0);
        acc[mt][nt] = __builtin_amdgcn_mfma_f32_16x16x32_bf16(aH[mt][0],   bw[nt][2].v, acc[mt][nt], 0, 0, 0);
        acc[mt][nt] = __builtin_amdgcn_mfma_f32_16x16x32_bf16(aH[mt][1],   bw[nt][3].v, acc[mt][nt], 0, 0, 0);
      }

    #pragma unroll
    for (int mt = 0; mt < 2; ++mt)
      #pragma unroll
      for (int nt = 0; nt < 4; ++nt)
        #pragma unroll
        for (int r = 0; r < 4; ++r) {
          float v = acc[mt][nt][r] + bp[nt];
          vmax[nt] = fmaxf(fmaxf(v, 0.f), vmax[nt]);
        }
  }

  #pragma unroll
  for (int nt = 0; nt < 4; ++nt) {
    vmax[nt] = fmaxf(vmax[nt], __shfl_xor(vmax[nt], 16, 64));
    vmax[nt] = fmaxf(vmax[nt], __shfl_xor(vmax[nt], 32, 64));
  }
  if (lane < 16) {
    #pragma unroll
    for (int nt = 0; nt < 4; ++nt) red[wave][nt * 16 + lane] = vmax[nt];
  }
  __syncthreads();

  if (tid < 64) {
    const int o = tid;
    const bool isf32 = (smallf[OFF_FLAG] != 0.0f);
    float pooled = fmaxf(fmaxf(red[0][o], red[1][o]), fmaxf(red[2][o], red[3][o]));
    float p0 = pooled * smallf[OFF_WPOS + o * 2 + 0];
    float p1 = pooled * smallf[OFF_WPOS + o * 2 + 1];
    #pragma unroll
    for (int sft = 32; sft >= 1; sft >>= 1) {
      p0 += __shfl_xor(p0, sft, 64);
      p1 += __shfl_xor(p1, sft, 64);
    }
    p0 += smallf[OFF_BPOS + 0];
    p1 += smallf[OFF_BPOS + 1];
    if (o == 0) {
      stout(out, i * 40 + (OBS + t) * 2 + 0, p0, isf32);
      stout(out, i * 40 + (OBS + t) * 2 + 1, p1, isf32);
      last_out[2 * i]     = p0;
      last_out[2 * i + 1] = p1;
    }
    float gir = 0.f, giz = 0.f, gin = 0.f, ghr = 0.f, ghz = 0.f, ghn = 0.f;
    #pragma unroll 8
    for (int k = 0; k < 64; ++k) {
      float ek = p0 * smallf[OFF_WEMB + k] + p1 * smallf[OFF_WEMB + 64 + k]
               + smallf[OFF_BEMB + k];
      float hk = h_carry[i * 64 + k];
      const float* w = WTf + k * 384;
      gir += ek * w[o];
      giz += ek * w[64 + o];
      gin += ek * w[128 + o];
      ghr += hk * w[192 + o];
      ghz += hk * w[256 + o];
      ghn += hk * w[320 + o];
    }
    gir += smallf[OFF_BIH + o];       ghr += smallf[OFF_BHH + o];
    giz += smallf[OFF_BIH + 64 + o];  ghz += smallf[OFF_BHH + 64 + o];
    gin += smallf[OFF_BIH + 128 + o]; ghn += smallf[OFF_BHH + 128 + o];
    float r = 1.f / (1.f + __expf(-(gir + ghr)));
    float z = 1.f / (1.f + __expf(-(giz + ghz)));
    float n = tanhf(gin + r * ghn);
    float hp = h_carry[i * 64 + o];
    float hn = (1.f - z) * n + z * hp;
    h_carry[i * 64 + o] = hn;
    hbf_out[i * 64 + o] = f2bf(hn);
  }
}

// ---------------------------------------------------------------------------
extern "C" void kernel_launch(void* const* d_in, const int* in_sizes, int n_in,
                              void* d_out, int out_size, void* d_ws, size_t ws_size,
                              hipStream_t stream) {
  (void)in_sizes; (void)n_in; (void)out_size;
  const void* hidden_state = d_in[0];
  const void* group_track  = d_in[1];
  const void* W_emb  = d_in[2];
  const void* b_emb  = d_in[3];
  const void* W_ih   = d_in[4];
  const void* W_hh   = d_in[5];
  const void* b_ih   = d_in[6];
  const void* b_hh   = d_in[7];
  const void* W_pos  = d_in[8];
  const void* b_pos  = d_in[9];
  const void* W_rel  = d_in[10];
  const void* b_rel  = d_in[11];
  const void* W_pool = d_in[12];
  const void* b_pool = d_in[13];

  char* ws = (char*)d_ws;

  if (ws_size >= WS_TOTAL) {
    unsigned*       bar      = (unsigned*)(ws + WS_BAR);
    float*          smallf   = (float*)(ws + WS_SMALL);
    float*          WTf      = (float*)(ws + WS_WTF);
    unsigned short* Wp_bf    = (unsigned short*)(ws + WS_WPBF);
    float2*         lastbase = (float2*)(ws + WS_LAST);
    unsigned short* hbfbase  = (unsigned short*)(ws + WS_HBF);

    init_kernel<<<1, 128, 0, stream>>>(bar);
    fused_kernel<<<NBLK, 512, 0, stream>>>(hidden_state, group_track,
                                           W_emb, b_emb, W_ih, W_hh, b_ih, b_hh,
                                           W_pos, b_pos, W_rel, b_rel,
                                           W_pool, b_pool,
                                           lastbase, hbfbase,
                                           WTf, Wp_bf, smallf, bar, d_out);
    return;
  }

  // ---- fallback: known-good 13-launch path, old compact layout ----
  float* lastA            = (float*)(ws + 0);
  float* lastB            = (float*)(ws + 4096);
  unsigned short* hbfA    = (unsigned short*)(ws + 8192);
  unsigned short* hbfB    = (unsigned short*)(ws + 73728);
  float* h_carry          = (float*)(ws + 139264);
  float* WTf              = (float*)(ws + 270336);
  unsigned short* Wp_bf   = (unsigned short*)(ws + 368640);
  float* smallf           = (float*)(ws + 385024);

  prep_kernel<<<512, 64, 0, stream>>>(hidden_state, group_track,
                                      W_emb, b_emb, W_ih, W_hh, b_ih, b_hh,
                                      W_pos, b_pos, W_rel, b_rel, W_pool, b_pool,
                                      lastA, hbfA, h_carry, WTf, Wp_bf,
                                      smallf, d_out);
  float* lastBuf[2] = {lastA, lastB};
  unsigned short* hbfBuf[2] = {hbfA, hbfB};
  for (int t = 0; t < PRE; ++t) {
    int p = t & 1;
    pair_kernel<<<512, 256, 0, stream>>>(smallf, Wp_bf, WTf,
                                         lastBuf[p], lastBuf[1 - p],
                                         hbfBuf[p], hbfBuf[1 - p],
                                         h_carry, d_out, t);
  }
}

// Round 9
// 235.167 us; speedup vs baseline: 3.2765x; 1.1148x over previous
//
#include <hip/hip_runtime.h>
#include <math.h>

// Problem constants
#define NB   512   // B (agents)
#define NH   64    // H = E = HP
#define OBS  8
#define PRE  12

// small f32 param pack offsets (elements)
#define OFF_WREL  0     // 128
#define OFF_BREL  128   // 64
#define OFF_BPOOL 192   // 64
#define OFF_WPOS  256   // 128
#define OFF_BPOS  384   // 2
#define OFF_WEMB  386   // 128
#define OFF_BEMB  514   // 64
#define OFF_BIH   578   // 192
#define OFF_BHH   770   // 192
#define OFF_FLAG  962   // 1: 1.0 if buffers are f32, 0.0 if bf16
#define N_SMALL   963

// ---- fused-path workspace layout (page-gapped write-once buffers) ----------
#define WS_BAR    0         // 4096 B (barrier counters, zeroed by init_kernel)
#define WS_SMALL  4096      // 4096 B (963 f32 used)
#define WS_WTF    8192      // 98304 B
#define WS_WPBF   106496    // 16384 B
#define WS_LAST   122880    // 13 * 8192 B   (4 KB data + 4 KB page gap each)
#define WS_HBF    229376    // 13 * 69632 B  (64 KB data + 4 KB page gap each)
#define WS_TOTAL  1134592
#define LAST_STRIDE_F2  1024   // float2 elems per last buffer slot
#define HBF_STRIDE_U16  34816  // u16 elems per hbf buffer slot

typedef __bf16 bf16x8 __attribute__((ext_vector_type(8)));
typedef float  f32x4  __attribute__((ext_vector_type(4)));

union FragU { bf16x8 v; unsigned short u[8]; };

__device__ __forceinline__ float bf2f(unsigned short u) {
  unsigned int x = ((unsigned int)u) << 16;
  return __builtin_bit_cast(float, x);
}
__device__ __forceinline__ unsigned short f2bf(float f) {
  unsigned int u = __builtin_bit_cast(unsigned int, f);
  u += 0x7FFFu + ((u >> 16) & 1u);   // RNE
  return (unsigned short)(u >> 16);
}
__device__ __forceinline__ float ldf(const void* p, int i, bool isf32) {
  return isf32 ? ((const float*)p)[i] : bf2f(((const unsigned short*)p)[i]);
}
__device__ __forceinline__ unsigned short ld16(const void* p, int i, bool isf32) {
  return isf32 ? f2bf(((const float*)p)[i]) : ((const unsigned short*)p)[i];
}
__device__ __forceinline__ void stout(void* p, int i, float v, bool isf32) {
  if (isf32) ((float*)p)[i] = v;
  else       ((unsigned short*)p)[i] = f2bf(v);
}

// ---- device-coherent stores: write-through to the IC coherence point so
// consumers on other XCDs see fresh data on their (plain, cached) first touch.
__device__ __forceinline__ void st32_sc(unsigned* p, unsigned v) {
  __hip_atomic_store(p, v, __ATOMIC_RELAXED, __HIP_MEMORY_SCOPE_AGENT);
}
__device__ __forceinline__ void stf_sc(float* p, float v) {
  __hip_atomic_store(p, v, __ATOMIC_RELAXED, __HIP_MEMORY_SCOPE_AGENT);
}
__device__ __forceinline__ void st64_sc(void* p, unsigned long long v) {
  __hip_atomic_store((unsigned long long*)p, v, __ATOMIC_RELAXED, __HIP_MEMORY_SCOPE_AGENT);
}

// ---- 2-level tree barrier in workspace. bar[0..31]=leaf, bar[64]=root,
// bar[96]=release (round count). Counters monotonic; init_kernel zeroes.
// 512 blocks = 32 leaves x 16.
// FULL version (entry __syncthreads drains ALL waves' stores via the
// compiler's waitcnt-before-s_barrier): use when multiple waves produced
// cross-block data (prep).
// FAST version (no entry sync): use when only wave 0 produced cross-block
// data -- tid 0's own vmcnt(0) covers it; the trailing __syncthreads both
// releases the block and orders wave-0's LDS writes (hstate) for all waves.
__device__ __forceinline__ void grid_barrier_core(unsigned* bar, unsigned phase,
                                                  int tid, int bid) {
  if (tid == 0) {
    asm volatile("s_waitcnt vmcnt(0)" ::: "memory");
    unsigned prev = __hip_atomic_fetch_add(&bar[bid & 31], 1u,
                                           __ATOMIC_RELAXED, __HIP_MEMORY_SCOPE_AGENT);
    if ((prev & 15u) == 15u) {
      unsigned r = __hip_atomic_fetch_add(&bar[64], 1u,
                                          __ATOMIC_RELAXED, __HIP_MEMORY_SCOPE_AGENT);
      if ((r & 31u) == 31u) {
        __hip_atomic_store(&bar[96], (r >> 5) + 1u,
                           __ATOMIC_RELAXED, __HIP_MEMORY_SCOPE_AGENT);
      }
    }
    while (__hip_atomic_load(&bar[96], __ATOMIC_RELAXED,
                             __HIP_MEMORY_SCOPE_AGENT) < phase)
      __builtin_amdgcn_s_sleep(8);
  }
  __syncthreads();
}
__device__ __forceinline__ void grid_barrier_full(unsigned* bar, unsigned phase,
                                                  int tid, int bid) {
  __syncthreads();
  grid_barrier_core(bar, phase, tid, bid);
}

__global__ __launch_bounds__(128) void init_kernel(unsigned* bar) {
  bar[threadIdx.x] = 0;
}

// ---------------------------------------------------------------------------
// FUSED persistent kernel: prep + all 12 decoder steps. 512 blocks x 256
// threads (4 waves, one agent per block) -- the round-4 proven geometry:
// __launch_bounds__(256,2) -> 128 VGPR zero-spill; capacity 4 blocks/CU
// for 512 blocks = 2x residency slack (rule from rounds 5/7 failures).
// This round: VALU-diet inner loop (native bf16 cvt, max3 epilogue with
// deferred bias/relu), li kept in register, lpos LDS stage removed (direct
// cached loads), fast barrier in the decode loop.
// ---------------------------------------------------------------------------
__global__ __launch_bounds__(256, 2) void fused_kernel(
    const void* __restrict__ hidden_state, // (1,512,64)
    const void* __restrict__ group_track,  // (512,8,2)
    const void* __restrict__ W_emb,  const void* __restrict__ b_emb,
    const void* __restrict__ W_ih,   const void* __restrict__ W_hh,
    const void* __restrict__ b_ih,   const void* __restrict__ b_hh,
    const void* __restrict__ W_pos,  const void* __restrict__ b_pos,
    const void* __restrict__ W_rel,  const void* __restrict__ b_rel,
    const void* __restrict__ W_pool, const void* __restrict__ b_pool,
    float2* __restrict__ lastbase,         // 13 slots, stride LAST_STRIDE_F2
    unsigned short* __restrict__ hbfbase,  // 13 slots, stride HBF_STRIDE_U16
    float* __restrict__ WTf,               // (64,384) f32 transposed GRU W
    unsigned short* __restrict__ Wp_bf,    // (128,64) bf16 W_pool
    float* __restrict__ smallf,            // N_SMALL f32 param pack
    unsigned* __restrict__ bar,            // barrier counters (zeroed)
    void* __restrict__ out)                // (512,20,2) dtype = input dtype
{
  const int i    = blockIdx.x;
  const int tid  = threadIdx.x;   // 0..255
  const int lane = tid & 63;
  const int wave = tid >> 6;      // 0..3
  const int col  = lane & 15;     // MFMA m (A rows) / n (B cols) index
  const int quad = lane >> 4;     // selects k-group (quad*8 .. quad*8+7)

  __shared__ float red[4][64];
  __shared__ float part[4][6][64];
  __shared__ float hstate[64];           // this agent's f32 GRU carry

  // ======================= prep ==========================
  // dtype detect: bf16-interpret first 256 u16 of hidden_state. Identical
  // wave-uniform result in every wave.
  int bad = 0;
  const unsigned short* hs16 = (const unsigned short*)hidden_state;
  for (int k = lane; k < 256; k += 64) {
    unsigned e = (hs16[k] >> 7) & 0xFFu;
    bad |= (e >= 0x8Eu) ? 1 : 0;
  }
  const bool isf32 = (__ballot(bad) != 0ULL);

  if (tid < 32) {                      // own h0 row -> bf16 (u32 pairs), sc
    unsigned lo = ld16(hidden_state, i * 64 + 2 * tid,     isf32);
    unsigned hi = ld16(hidden_state, i * 64 + 2 * tid + 1, isf32);
    st32_sc((unsigned*)hbfbase + i * 32 + tid, lo | (hi << 16));
  }
  if (tid < 64) hstate[tid] = 0.0f;
  if (tid < 16) stout(out, i * 40 + tid, ldf(group_track, i * 16 + tid, isf32), isf32);
  // own last position -> register (ALL threads; identical value), and the
  // step-0 buffer for other blocks (one sc-store).
  float2 li;
  li.x = ldf(group_track, i * 16 + 14, isf32);
  li.y = ldf(group_track, i * 16 + 15, isf32);
  if (tid == 0)
    st64_sc(lastbase + i, __builtin_bit_cast(unsigned long long, li));

  if (i < 96) {                      // WTf: 24576 elems = 96 blocks x 256
    int u = i * 256 + tid;
    int k = u / 384, c = u % 384;
    float v = (c < 192) ? ldf(W_ih, c * 64 + k, isf32)
                        : ldf(W_hh, (c - 192) * 64 + k, isf32);
    stf_sc(&WTf[u], v);
  } else if (i < 112) {              // Wp_bf: 4096 u32 = 16 blocks x 256
    int u = (i - 96) * 256 + tid;
    unsigned lo = ld16(W_pool, 2 * u,     isf32);
    unsigned hi = ld16(W_pool, 2 * u + 1, isf32);
    st32_sc((unsigned*)Wp_bf + u, lo | (hi << 16));
  } else if (i >= 128 && i < 132) {  // smallf pack: 963 elems
    int u = (i - 128) * 256 + tid;
    if (u < N_SMALL) {
      float v;
      if      (u < 128) v = ldf(W_rel,  u,        isf32);
      else if (u < 192) v = ldf(b_rel,  u - 128,  isf32);
      else if (u < 256) v = ldf(b_pool, u - 192,  isf32);
      else if (u < 384) v = ldf(W_pos,  u - 256,  isf32);
      else if (u < 386) v = ldf(b_pos,  u - 384,  isf32);
      else if (u < 514) v = ldf(W_emb,  u - 386,  isf32);
      else if (u < 578) v = ldf(b_emb,  u - 514,  isf32);
      else if (u < 770) v = ldf(b_ih,   u - 578,  isf32);
      else if (u < 962) v = ldf(b_hh,   u - 770,  isf32);
      else              v = isf32 ? 1.0f : 0.0f;   // OFF_FLAG
      stf_sc(&smallf[u], v);
    }
  }
  grid_barrier_full(bar, 1u, tid, i);   // prep: many waves stored -> full

  // =================== persistent per-lane fragments =======================
  // Write-once data: plain cached loads, first touch is after the barrier.
  float wr0[2][8], wr1[2][8], brl[2][8];
  #pragma unroll
  for (int ks = 0; ks < 2; ++ks) {
    int kb = ks * 32 + quad * 8;
    #pragma unroll
    for (int j = 0; j < 8; ++j) {
      wr0[ks][j] = smallf[OFF_WREL + kb + j];
      wr1[ks][j] = smallf[OFF_WREL + 64 + kb + j];
      brl[ks][j] = smallf[OFF_BREL + kb + j];
    }
  }
  float bp[4];
  #pragma unroll
  for (int nt = 0; nt < 4; ++nt) bp[nt] = smallf[OFF_BPOOL + nt * 16 + col];

  // B-operand fragments of full W_pool (K=128): lane holds
  // B[k = ks*32 + quad*8 + j][n = nt*16 + col]
  FragU bw[4][4];
  #pragma unroll
  for (int nt = 0; nt < 4; ++nt)
    #pragma unroll
    for (int ks = 0; ks < 4; ++ks)
      #pragma unroll
      for (int j = 0; j < 8; ++j)
        bw[nt][ks].u[j] = Wp_bf[(ks * 32 + quad * 8 + j) * 64 + nt * 16 + col];

  // ========================== decode loop ==================================
  for (int t = 0; t < PRE; ++t) {
    // step-t buffers are ready (barrier passed); all loads below are plain.
    const float2*         lp       = lastbase + t * LAST_STRIDE_F2;
    float2*               last_out = lastbase + (t + 1) * LAST_STRIDE_F2;
    const unsigned short* hbf_in   = hbfbase + t * HBF_STRIDE_U16;
    unsigned short*       hbf_out  = hbfbase + (t + 1) * HBF_STRIDE_U16;

    float mx[4] = {-3.0e38f, -3.0e38f, -3.0e38f, -3.0e38f};

    // --- j loop: this wave covers rows [wave*128, wave*128+128), 32 at a time
    const int jb0 = wave * 128;
    for (int s = 0; s < 4; ++s) {
      const int jb = jb0 + s * 32;
      const int r0 = jb + col, r1 = r0 + 16;
      const float2 l0 = lp[r0], l1 = lp[r1];   // direct cached loads
      const float d0x = l0.x - li.x, d0y = l0.y - li.y;
      const float d1x = l1.x - li.x, d1y = l1.y - li.y;

      // A-fragments for e-part (K rows 0..63): native bf16 casts (hardware
      // cvt, RNE) replace the 5-op software round-shift.
      bf16x8 aE[2][2];
      #pragma unroll
      for (int ks = 0; ks < 2; ++ks) {
        #pragma unroll
        for (int j = 0; j < 8; ++j) {
          float e0 = fmaxf(d0x * wr0[ks][j] + d0y * wr1[ks][j] + brl[ks][j], 0.f);
          float e1 = fmaxf(d1x * wr0[ks][j] + d1y * wr1[ks][j] + brl[ks][j], 0.f);
          aE[0][ks][j] = (__bf16)e0;
          aE[1][ks][j] = (__bf16)e1;
        }
      }
      // A-fragments for h-part (K rows 64..127): plain 16B vector loads
      bf16x8 aH[2][2];
      #pragma unroll
      for (int mt = 0; mt < 2; ++mt) {
        int jr = jb + mt * 16 + col;
        #pragma unroll
        for (int ks = 0; ks < 2; ++ks)
          aH[mt][ks] = *(const bf16x8*)(hbf_in + jr * 64 + ks * 32 + quad * 8);
      }

      f32x4 acc[2][4];
      #pragma unroll
      for (int mt = 0; mt < 2; ++mt)
        #pragma unroll
        for (int nt = 0; nt < 4; ++nt)
          acc[mt][nt] = (f32x4){0.f, 0.f, 0.f, 0.f};

      #pragma unroll
      for (int nt = 0; nt < 4; ++nt)
        #pragma unroll
        for (int mt = 0; mt < 2; ++mt) {
          acc[mt][nt] = __builtin_amdgcn_mfma_f32_16x16x32_bf16(aE[mt][0], bw[nt][0].v, acc[mt][nt], 0, 0, 0);
          acc[mt][nt] = __builtin_amdgcn_mfma_f32_16x16x32_bf16(aE[mt][1], bw[nt][1].v, acc[mt][nt], 0, 0, 0);
          acc[mt][nt] = __builtin_amdgcn_mfma_f32_16x16x32_bf16(aH[mt][0], bw[nt][2].v, acc[mt][nt], 0, 0, 0);
          acc[mt][nt] = __builtin_amdgcn_mfma_f32_16x16x32_bf16(aH[mt][1], bw[nt][3].v, acc[mt][nt], 0, 0, 0);
        }

      // epilogue: pure running max (bias+relu deferred; pairs -> v_max3)
      #pragma unroll
      for (int mt = 0; mt < 2; ++mt)
        #pragma unroll
        for (int nt = 0; nt < 4; ++nt) {
          float m01 = fmaxf(acc[mt][nt][0], acc[mt][nt][1]);
          float m23 = fmaxf(acc[mt][nt][2], acc[mt][nt][3]);
          mx[nt] = fmaxf(fmaxf(m01, m23), mx[nt]);
        }
    }

    // deferred bias + relu (max is monotone-commutative with relu(x+b)),
    // then reduce over quads within the wave, publish per-wave max
    float vmax[4];
    #pragma unroll
    for (int nt = 0; nt < 4; ++nt) {
      vmax[nt] = fmaxf(mx[nt] + bp[nt], 0.f);
      vmax[nt] = fmaxf(vmax[nt], __shfl_xor(vmax[nt], 16, 64));
      vmax[nt] = fmaxf(vmax[nt], __shfl_xor(vmax[nt], 32, 64));
    }
    if (lane < 16) {
      #pragma unroll
      for (int nt = 0; nt < 4; ++nt) red[wave][nt * 16 + lane] = vmax[nt];
    }
    __syncthreads();   // sync1: red[] complete; hstate stable from prev step

    // ---------------- head: pos -> emb -> GRU, 4-way wave-parallel ---------
    {
      const int o = lane;
      float pooled = fmaxf(fmaxf(red[0][o], red[1][o]), fmaxf(red[2][o], red[3][o]));
      float p0 = pooled * smallf[OFF_WPOS + o * 2 + 0];
      float p1 = pooled * smallf[OFF_WPOS + o * 2 + 1];
      #pragma unroll
      for (int sft = 32; sft >= 1; sft >>= 1) {
        p0 += __shfl_xor(p0, sft, 64);
        p1 += __shfl_xor(p1, sft, 64);
      }
      p0 += smallf[OFF_BPOS + 0];
      p1 += smallf[OFF_BPOS + 1];

      // wave w accumulates k in [16w, 16w+16): partial 6 gate mat-vecs
      float g0 = 0.f, g1 = 0.f, g2 = 0.f, g3 = 0.f, g4 = 0.f, g5 = 0.f;
      #pragma unroll 8
      for (int kk = 0; kk < 16; ++kk) {
        int k = wave * 16 + kk;
        float ek = p0 * smallf[OFF_WEMB + k] + p1 * smallf[OFF_WEMB + 64 + k]
                 + smallf[OFF_BEMB + k];          // emb_k (uniform)
        float hk = hstate[k];                     // uniform LDS broadcast
        const float* w = WTf + k * 384;           // coalesced across lanes
        g0 += ek * w[o];
        g1 += ek * w[64 + o];
        g2 += ek * w[128 + o];
        g3 += hk * w[192 + o];
        g4 += hk * w[256 + o];
        g5 += hk * w[320 + o];
      }
      part[wave][0][o] = g0; part[wave][1][o] = g1; part[wave][2][o] = g2;
      part[wave][3][o] = g3; part[wave][4][o] = g4; part[wave][5][o] = g5;
      __syncthreads();   // sync2: partials complete; hstate reads done

      if (wave == 0) {
        float gir = 0.f, giz = 0.f, gin = 0.f, ghr = 0.f, ghz = 0.f, ghn = 0.f;
        #pragma unroll
        for (int pp = 0; pp < 4; ++pp) {
          gir += part[pp][0][o]; giz += part[pp][1][o]; gin += part[pp][2][o];
          ghr += part[pp][3][o]; ghz += part[pp][4][o]; ghn += part[pp][5][o];
        }
        gir += smallf[OFF_BIH + o];       ghr += smallf[OFF_BHH + o];
        giz += smallf[OFF_BIH + 64 + o];  ghz += smallf[OFF_BHH + 64 + o];
        gin += smallf[OFF_BIH + 128 + o]; ghn += smallf[OFF_BHH + 128 + o];
        float r = 1.f / (1.f + __expf(-(gir + ghr)));
        float z = 1.f / (1.f + __expf(-(giz + ghz)));
        float n = tanhf(gin + r * ghn);
        float hp = hstate[o];
        float hn = (1.f - z) * n + z * hp;
        hstate[o] = hn;                      // safe: all reads were pre-sync2
        // pack bf16 pairs, sc-store as u32 into next step's write-once buf
        int hbi = (int)f2bf(hn);
        unsigned v0 = (unsigned)__shfl(hbi, (o & 31) * 2, 64);
        unsigned v1 = (unsigned)__shfl(hbi, (o & 31) * 2 + 1, 64);
        if (o < 32)
          st32_sc((unsigned*)hbf_out + i * 32 + o, v0 | (v1 << 16));
        if (o == 0) {
          stout(out, i * 40 + (OBS + t) * 2 + 0, p0, isf32);
          stout(out, i * 40 + (OBS + t) * 2 + 1, p1, isf32);
          float2 pr; pr.x = p0; pr.y = p1;
          st64_sc(last_out + i, __builtin_bit_cast(unsigned long long, pr));
        }
      }
      // all threads computed identical p0,p1 = this agent's new position:
      // keep own li in register for the next step (no reload after barrier)
      li.x = p0;
      li.y = p1;
    }

    // fast barrier: only wave 0 produced cross-block data; tid 0 (wave 0)
    // drains its own stores with vmcnt(0); trailing __syncthreads releases
    // the block and orders wave-0's hstate write for next step's readers.
    if (t < PRE - 1) grid_barrier_core(bar, (unsigned)(t + 2), tid, i);
  }
}

// ---------------------------------------------------------------------------
// FALLBACK path (known-good 13-launch version) if workspace is too small.
// Uses its own (old) compact workspace layout.
// ---------------------------------------------------------------------------
__global__ __launch_bounds__(64) void prep_kernel(
    const void* __restrict__ hidden_state,
    const void* __restrict__ group_track,
    const void* __restrict__ W_emb,  const void* __restrict__ b_emb,
    const void* __restrict__ W_ih,   const void* __restrict__ W_hh,
    const void* __restrict__ b_ih,   const void* __restrict__ b_hh,
    const void* __restrict__ W_pos,  const void* __restrict__ b_pos,
    const void* __restrict__ W_rel,  const void* __restrict__ b_rel,
    const void* __restrict__ W_pool, const void* __restrict__ b_pool,
    float* __restrict__ last0,
    unsigned short* __restrict__ hbf0,
    float* __restrict__ h_carry,
    float* __restrict__ WTf,
    unsigned short* __restrict__ Wp_bf,
    float* __restrict__ smallf,
    void* __restrict__ out)
{
  const int b = blockIdx.x;
  const int o = threadIdx.x;

  int bad = 0;
  const unsigned short* hs16 = (const unsigned short*)hidden_state;
  for (int k = o; k < 256; k += 64) {
    unsigned e = (hs16[k] >> 7) & 0xFFu;
    bad |= (e >= 0x8Eu) ? 1 : 0;
  }
  const bool isf32 = (__ballot(bad) != 0ULL);

  hbf0[b * 64 + o] = ld16(hidden_state, b * 64 + o, isf32);
  h_carry[b * 64 + o] = 0.0f;
  if (o < 16) stout(out, b * 40 + o, ldf(group_track, b * 16 + o, isf32), isf32);
  if (o < 2)  last0[b * 2 + o] = ldf(group_track, b * 16 + 14 + o, isf32);

  if (b < 384) {
    int u = b * 64 + o;
    int k = u / 384, c = u % 384;
    WTf[u] = (c < 192) ? ldf(W_ih, c * 64 + k, isf32)
                       : ldf(W_hh, (c - 192) * 64 + k, isf32);
  } else {
    int u = (b - 384) * 64 + o;
    Wp_bf[u] = ld16(W_pool, u, isf32);
  }

  if (b < 16) {
    int u = b * 64 + o;
    if (u < N_SMALL) {
      float v;
      if      (u < 128) v = ldf(W_rel,  u,        isf32);
      else if (u < 192) v = ldf(b_rel,  u - 128,  isf32);
      else if (u < 256) v = ldf(b_pool, u - 192,  isf32);
      else if (u < 384) v = ldf(W_pos,  u - 256,  isf32);
      else if (u < 386) v = ldf(b_pos,  u - 384,  isf32);
      else if (u < 514) v = ldf(W_emb,  u - 386,  isf32);
      else if (u < 578) v = ldf(b_emb,  u - 514,  isf32);
      else if (u < 770) v = ldf(b_ih,   u - 578,  isf32);
      else if (u < 962) v = ldf(b_hh,   u - 770,  isf32);
      else              v = isf32 ? 1.0f : 0.0f;
      smallf[u] = v;
    }
  }
}

__global__ __launch_bounds__(256) void pair_kernel(
    const float* __restrict__ smallf,
    const unsigned short* __restrict__ Wp_bf,
    const float* __restrict__ WTf,
    const float* __restrict__ last_in,
    float* __restrict__ last_out,
    const unsigned short* __restrict__ hbf_in,
    unsigned short* __restrict__ hbf_out,
    float* __restrict__ h_carry,
    void* __restrict__ out,
    int t)
{
  const int i    = blockIdx.x;
  const int tid  = threadIdx.x;
  const int lane = tid & 63;
  const int wave = tid >> 6;
  const int col  = lane & 15;
  const int quad = lane >> 4;

  __shared__ float red[4][64];

  const float2* lp = (const float2*)last_in;
  const float2  li = lp[i];

  float wr0[2][8], wr1[2][8], brl[2][8];
  #pragma unroll
  for (int ks = 0; ks < 2; ++ks) {
    int kb = ks * 32 + quad * 8;
    #pragma unroll
    for (int j = 0; j < 8; ++j) {
      wr0[ks][j] = smallf[OFF_WREL + kb + j];
      wr1[ks][j] = smallf[OFF_WREL + 64 + kb + j];
      brl[ks][j] = smallf[OFF_BREL + kb + j];
    }
  }
  float bp[4];
  #pragma unroll
  for (int nt = 0; nt < 4; ++nt) bp[nt] = smallf[OFF_BPOOL + nt * 16 + col];

  FragU bw[4][4];
  #pragma unroll
  for (int nt = 0; nt < 4; ++nt)
    #pragma unroll
    for (int ks = 0; ks < 4; ++ks)
      #pragma unroll
      for (int j = 0; j < 8; ++j)
        bw[nt][ks].u[j] = Wp_bf[(ks * 32 + quad * 8 + j) * 64 + nt * 16 + col];

  float vmax[4] = {0.f, 0.f, 0.f, 0.f};

  const int jb0 = wave * 128;
  for (int s = 0; s < 4; ++s) {
    const int jb = jb0 + s * 32;
    const int r0 = jb + col, r1 = r0 + 16;
    const float2 l0 = lp[r0], l1 = lp[r1];
    const float d0x = l0.x - li.x, d0y = l0.y - li.y;
    const float d1x = l1.x - li.x, d1y = l1.y - li.y;

    FragU aE[2][2];
    #pragma unroll
    for (int ks = 0; ks < 2; ++ks) {
      #pragma unroll
      for (int j = 0; j < 8; ++j) {
        float e0 = fmaxf(d0x * wr0[ks][j] + d0y * wr1[ks][j] + brl[ks][j], 0.f);
        float e1 = fmaxf(d1x * wr0[ks][j] + d1y * wr1[ks][j] + brl[ks][j], 0.f);
        aE[0][ks].u[j] = f2bf(e0);
        aE[1][ks].u[j] = f2bf(e1);
      }
    }
    bf16x8 aH[2][2];
    #pragma unroll
    for (int mt = 0; mt < 2; ++mt) {
      int jr = jb + mt * 16 + col;
      #pragma unroll
      for (int ks = 0; ks < 2; ++ks)
        aH[mt][ks] = *(const bf16x8*)(hbf_in + jr * 64 + ks * 32 + quad * 8);
    }

    f32x4 acc[2][4];
    #pragma unroll
    for (int mt = 0; mt < 2; ++mt)
      #pragma unroll
      for (int nt = 0; nt < 4; ++nt)
        acc[mt][nt] = (f32x4){0.f, 0.f, 0.f, 0.f};

    #pragma unroll
    for (int nt = 0; nt < 4; ++nt)
      #pragma unroll
      for (int mt = 0; mt < 2; ++mt) {
        acc[mt][nt] = __builtin_amdgcn_mfma_f32_16x16x32_bf16(aE[mt][0].v, bw[nt][0].v, acc[mt][nt], 0, 0, 0);
        acc[mt][nt] = __builtin_amdgcn_mfma_f32_16x16x32_bf16(aE[mt][1].v, bw[nt][1].v, acc[mt][nt], 0, 0, 0);
        acc[mt][nt] = __builtin_amdgcn_mfma_f32_16x16x32_bf16(aH[mt][0],   bw[nt][2].v, acc[mt][nt], 0, 0, 0);
        acc[mt][nt] = __builtin_amdgcn_mfma_f32_16x16x32_bf16(aH[mt][1],   bw[nt][3].v, acc[mt][nt], 0, 0, 0);
      }

    #pragma unroll
    for (int mt = 0; mt < 2; ++mt)
      #pragma unroll
      for (int nt = 0; nt < 4; ++nt)
        #pragma unroll
        for (int r = 0; r < 4; ++r) {
          float v = acc[mt][nt][r] + bp[nt];
          vmax[nt] = fmaxf(fmaxf(v, 0.f), vmax[nt]);
        }
  }

  #pragma unroll
  for (int nt = 0; nt < 4; ++nt) {
    vmax[nt] = fmaxf(vmax[nt], __shfl_xor(vmax[nt], 16, 64));
    vmax[nt] = fmaxf(vmax[nt], __shfl_xor(vmax[nt], 32, 64));
  }
  if (lane < 16) {
    #pragma unroll
    for (int nt = 0; nt < 4; ++nt) red[wave][nt * 16 + lane] = vmax[nt];
  }
  __syncthreads();

  if (tid < 64) {
    const int o = tid;
    const bool isf32 = (smallf[OFF_FLAG] != 0.0f);
    float pooled = fmaxf(fmaxf(red[0][o], red[1][o]), fmaxf(red[2][o], red[3][o]));
    float p0 = pooled * smallf[OFF_WPOS + o * 2 + 0];
    float p1 = pooled * smallf[OFF_WPOS + o * 2 + 1];
    #pragma unroll
    for (int sft = 32; sft >= 1; sft >>= 1) {
      p0 += __shfl_xor(p0, sft, 64);
      p1 += __shfl_xor(p1, sft, 64);
    }
    p0 += smallf[OFF_BPOS + 0];
    p1 += smallf[OFF_BPOS + 1];
    if (o == 0) {
      stout(out, i * 40 + (OBS + t) * 2 + 0, p0, isf32);
      stout(out, i * 40 + (OBS + t) * 2 + 1, p1, isf32);
      last_out[2 * i]     = p0;
      last_out[2 * i + 1] = p1;
    }
    float gir = 0.f, giz = 0.f, gin = 0.f, ghr = 0.f, ghz = 0.f, ghn = 0.f;
    #pragma unroll 8
    for (int k = 0; k < 64; ++k) {
      float ek = p0 * smallf[OFF_WEMB + k] + p1 * smallf[OFF_WEMB + 64 + k]
               + smallf[OFF_BEMB + k];
      float hk = h_carry[i * 64 + k];
      const float* w = WTf + k * 384;
      gir += ek * w[o];
      giz += ek * w[64 + o];
      gin += ek * w[128 + o];
      ghr += hk * w[192 + o];
      ghz += hk * w[256 + o];
      ghn += hk * w[320 + o];
    }
    gir += smallf[OFF_BIH + o];       ghr += smallf[OFF_BHH + o];
    giz += smallf[OFF_BIH + 64 + o];  ghz += smallf[OFF_BHH + 64 + o];
    gin += smallf[OFF_BIH + 128 + o]; ghn += smallf[OFF_BHH + 128 + o];
    float r = 1.f / (1.f + __expf(-(gir + ghr)));
    float z = 1.f / (1.f + __expf(-(giz + ghz)));
    float n = tanhf(gin + r * ghn);
    float hp = h_carry[i * 64 + o];
    float hn = (1.f - z) * n + z * hp;
    h_carry[i * 64 + o] = hn;
    hbf_out[i * 64 + o] = f2bf(hn);
  }
}

// ---------------------------------------------------------------------------
extern "C" void kernel_launch(void* const* d_in, const int* in_sizes, int n_in,
                              void* d_out, int out_size, void* d_ws, size_t ws_size,
                              hipStream_t stream) {
  (void)in_sizes; (void)n_in; (void)out_size;
  const void* hidden_state = d_in[0];
  const void* group_track  = d_in[1];
  const void* W_emb  = d_in[2];
  const void* b_emb  = d_in[3];
  const void* W_ih   = d_in[4];
  const void* W_hh   = d_in[5];
  const void* b_ih   = d_in[6];
  const void* b_hh   = d_in[7];
  const void* W_pos  = d_in[8];
  const void* b_pos  = d_in[9];
  const void* W_rel  = d_in[10];
  const void* b_rel  = d_in[11];
  const void* W_pool = d_in[12];
  const void* b_pool = d_in[13];

  char* ws = (char*)d_ws;

  if (ws_size >= WS_TOTAL) {
    unsigned*       bar      = (unsigned*)(ws + WS_BAR);
    float*          smallf   = (float*)(ws + WS_SMALL);
    float*          WTf      = (float*)(ws + WS_WTF);
    unsigned short* Wp_bf    = (unsigned short*)(ws + WS_WPBF);
    float2*         lastbase = (float2*)(ws + WS_LAST);
    unsigned short* hbfbase  = (unsigned short*)(ws + WS_HBF);

    init_kernel<<<1, 128, 0, stream>>>(bar);
    fused_kernel<<<NB, 256, 0, stream>>>(hidden_state, group_track,
                                         W_emb, b_emb, W_ih, W_hh, b_ih, b_hh,
                                         W_pos, b_pos, W_rel, b_rel,
                                         W_pool, b_pool,
                                         lastbase, hbfbase,
                                         WTf, Wp_bf, smallf, bar, d_out);
    return;
  }

  // ---- fallback: known-good 13-launch path, old compact layout ----
  float* lastA            = (float*)(ws + 0);
  float* lastB            = (float*)(ws + 4096);
  unsigned short* hbfA    = (unsigned short*)(ws + 8192);
  unsigned short* hbfB    = (unsigned short*)(ws + 73728);
  float* h_carry          = (float*)(ws + 139264);
  float* WTf              = (float*)(ws + 270336);
  unsigned short* Wp_bf   = (unsigned short*)(ws + 368640);
  float* smallf           = (float*)(ws + 385024);

  prep_kernel<<<512, 64, 0, stream>>>(hidden_state, group_track,
                                      W_emb, b_emb, W_ih, W_hh, b_ih, b_hh,
                                      W_pos, b_pos, W_rel, b_rel, W_pool, b_pool,
                                      lastA, hbfA, h_carry, WTf, Wp_bf,
                                      smallf, d_out);
  float* lastBuf[2] = {lastA, lastB};
  unsigned short* hbfBuf[2] = {hbfA, hbfB};
  for (int t = 0; t < PRE; ++t) {
    int p = t & 1;
    pair_kernel<<<512, 256, 0, stream>>>(smallf, Wp_bf, WTf,
                                         lastBuf[p], lastBuf[1 - p],
                                         hbfBuf[p], hbfBuf[1 - p],
                                         h_carry, d_out, t);
  }
}